// Round 8
// baseline (2068.451 us; speedup 1.0000x reference)
//
#include <hip/hip_runtime.h>
#include <hip/hip_bf16.h>
#include <stdint.h>

typedef unsigned short u16;
typedef unsigned int u32;
typedef unsigned long long u64;
typedef __attribute__((ext_vector_type(4))) float f32x4;
typedef __attribute__((ext_vector_type(8))) short s16x8;

#define AT_LD(p)    __hip_atomic_load((p), __ATOMIC_RELAXED, __HIP_MEMORY_SCOPE_AGENT)
#define AT_ST(p, v) __hip_atomic_store((p), (v), __ATOMIC_RELAXED, __HIP_MEMORY_SCOPE_AGENT)

// ---------- helpers ----------

static __device__ __forceinline__ u16 f2bf(float f) {
  union { float f; unsigned u; } v; v.f = f;
  unsigned r = v.u + 0x7FFFu + ((v.u >> 16) & 1u);
  return (u16)(r >> 16);
}

static __device__ __forceinline__ void gload_lds16(const void* g, void* l) {
  __builtin_amdgcn_global_load_lds(
      (const __attribute__((address_space(1))) unsigned int*)(uintptr_t)g,
      (__attribute__((address_space(3))) unsigned int*)(uintptr_t)l,
      16, 0, 0);
}

// bank-balancing swizzle for the 32KB h tile in LDS (see r6).
static __device__ __forceinline__ int swzB(int B) {
  int pos = (B >> 4) & 127;
  int row = (B >> 11) & 15;
  int slot = (pos ^ row ^ (pos >> 3)) & 7;
  int npos = (pos & 0x78) | slot;
  return (B & ~0x7F0) | (npos << 4);
}

// ---------- pre-pass kernels ----------

__global__ void embed_kernel(const int* __restrict__ inputs,
                             const float* __restrict__ emb,
                             u16* __restrict__ xbf) {
  int i = blockIdx.x * 256 + threadIdx.x;   // 131072 threads
  int row = i >> 6;
  int e0 = (i & 63) << 3;
  int tok = inputs[row];
  const float* src = emb + (size_t)tok * 512 + e0;
  s16x8 o;
#pragma unroll
  for (int j = 0; j < 8; ++j) o[j] = (short)f2bf(src[j]);
  *(s16x8*)(xbf + (size_t)row * 512 + e0) = o;
}

// bit-pack mask: maskb[b*2+h] bit j = (inputs[b*128 + h*64 + j] != 0)
__global__ void mask_kernel(const int* __restrict__ inputs, u64* __restrict__ mb) {
  int t = threadIdx.x;
  if (t < 32) {
    int b = t >> 1, h = t & 1;
    u64 m = 0;
    for (int j = 0; j < 64; ++j)
      m |= (u64)(inputs[b * 128 + h * 64 + j] != 0) << j;
    mb[t] = m;
  }
}

// Wt[n][k] = bf16(W[k][n]); K,N multiples of 32
__global__ void transpose_bf16(const float* __restrict__ W, u16* __restrict__ Wt,
                               int K, int N) {
  __shared__ float t[32][33];
  int ntn = N >> 5;
  int tn = blockIdx.x % ntn, tk = blockIdx.x / ntn;
  int n0 = tn << 5, k0 = tk << 5;
  int tx = threadIdx.x & 31, ty = threadIdx.x >> 5;  // ty 0..7
#pragma unroll
  for (int j = 0; j < 4; ++j) {
    int k = ty * 4 + j;
    t[k][tx] = W[(size_t)(k0 + k) * N + n0 + tx];
  }
  __syncthreads();
#pragma unroll
  for (int j = 0; j < 4; ++j) {
    int n = ty * 4 + j;
    Wt[(size_t)(n0 + n) * K + k0 + tx] = f2bf(t[tx][n]);
  }
}

// ---------- m97-style bf16 GEMM, 128x128 tile, BK=32 ----------
// MODE 0: C=f32, store acc+bias          (xg)
// MODE 1: C=bf16, store relu(acc+bias)   (d1)
// MODE 2: C=f32, store exp(acc+bias), atomicAdd row sums (logits->exp)
template <int MODE>
__global__ __launch_bounds__(256)
void gemm_bf16(const u16* __restrict__ A, const u16* __restrict__ Bt,
               const float* __restrict__ bias, void* __restrict__ Cptr,
               float* __restrict__ rowsum, int M, int N, int K) {
  (void)M;
  __shared__ u16 sA[128 * 32];
  __shared__ u16 sB[128 * 32];
  const int nbn = N >> 7;
  const int nwg = gridDim.x;
  int bid = blockIdx.x;
  int q = nwg >> 3;                         // grids are multiples of 8
  int swz = (bid & 7) * q + (bid >> 3);     // XCD-aware swizzle (bijective)
  int bm = swz / nbn, bn = swz % nbn;
  const int brow = bm << 7, bcol = bn << 7;

  const int tid = threadIdx.x;
  const int lane = tid & 63;
  const int wv = tid >> 6;
  const int wr = (wv >> 1) * 64, wc = (wv & 1) * 64;
  const int ln = lane & 15, kh = lane >> 4;

  const int srow = tid >> 2;                // 0..63
  const int kch = (tid & 3) << 3;           // 0,8,16,24 (elements)

  f32x4 acc[4][4] = {};

  const int nk = K >> 5;
  const u16* Abase = A + (size_t)(brow + srow) * K + kch;
  const u16* Bbase = Bt + (size_t)(bcol + srow) * K + kch;
  const size_t rstride = (size_t)64 * K;
  u16* lA = sA + srow * 32 + kch;
  u16* lB = sB + srow * 32 + kch;

  for (int kt = 0; kt < nk; ++kt) {
    const int k0 = kt << 5;
    gload_lds16(Abase + k0, lA);
    gload_lds16(Abase + rstride + k0, lA + 64 * 32);
    gload_lds16(Bbase + k0, lB);
    gload_lds16(Bbase + rstride + k0, lB + 64 * 32);
    __syncthreads();
    s16x8 aF[4], bF[4];
#pragma unroll
    for (int m = 0; m < 4; ++m)
      aF[m] = *(const s16x8*)(sA + (wr + m * 16 + ln) * 32 + kh * 8);
#pragma unroll
    for (int n = 0; n < 4; ++n)
      bF[n] = *(const s16x8*)(sB + (wc + n * 16 + ln) * 32 + kh * 8);
#pragma unroll
    for (int m = 0; m < 4; ++m)
#pragma unroll
      for (int n = 0; n < 4; ++n)
        acc[m][n] = __builtin_amdgcn_mfma_f32_16x16x32_bf16(aF[m], bF[n], acc[m][n], 0, 0, 0);
    __syncthreads();
  }

  const int browq = brow + wr;
  const int bcolq = bcol + wc;

  if (MODE == 1) {
    u16* O = (u16*)Cptr;
#pragma unroll
    for (int n = 0; n < 4; ++n) {
      int gcol = bcolq + n * 16 + ln;
      float bv = bias[gcol];
#pragma unroll
      for (int m = 0; m < 4; ++m)
#pragma unroll
        for (int r = 0; r < 4; ++r) {
          int grow = browq + m * 16 + kh * 4 + r;
          float v = fmaxf(acc[m][n][r] + bv, 0.f);
          O[(size_t)grow * N + gcol] = f2bf(v);
        }
    }
  } else {
    float* O = (float*)Cptr;
    float rs[4][4] = {};
#pragma unroll
    for (int n = 0; n < 4; ++n) {
      int gcol = bcolq + n * 16 + ln;
      float bv = bias[gcol];
#pragma unroll
      for (int m = 0; m < 4; ++m)
#pragma unroll
        for (int r = 0; r < 4; ++r) {
          int grow = browq + m * 16 + kh * 4 + r;
          float v = acc[m][n][r] + bv;
          if (MODE == 2) { v = __expf(v); rs[m][r] += v; }
          O[(size_t)grow * N + gcol] = v;
        }
    }
    if (MODE == 2) {
#pragma unroll
      for (int m = 0; m < 4; ++m)
#pragma unroll
        for (int r = 0; r < 4; ++r) {
          float v = rs[m][r];
          v += __shfl_xor(v, 1);
          v += __shfl_xor(v, 2);
          v += __shfl_xor(v, 4);
          v += __shfl_xor(v, 8);
          if (ln == 0) atomicAdd(&rowsum[browq + m * 16 + kh * 4 + r], v);
        }
    }
  }
}

// ---------- persistent LSTM, phase-ablated for instrumentation ----------
// PH bitmask: 1=stage, 2=mfma, 4=gates+publish, 8=sync.
// Real kernel = <128, 15>. Diagnostics (read-only on real buffers, own cnt):
//   <512, 8>  sync skeleton only  -> per-step lockstep sync cost
//   <256, 9>  stage+sync          -> per-step stage cost (incl. L3 contention)
template <int STEPS, int PH>
__global__ __launch_bounds__(512, 1)
void lstm_kernel(const float* __restrict__ xg,      // [2048][4096] f32
                 const u16* __restrict__ Wht,       // [4096][1024] bf16 (n-major)
                 const u64* __restrict__ maskb,     // [16][2] bitmask
                 const float* __restrict__ ench, const float* __restrict__ encc,
                 const float* __restrict__ gamma, const float* __restrict__ beta,
                 const float* __restrict__ mmean, const float* __restrict__ mvar,
                 u32* __restrict__ hbuf32,          // [2][16][512] u32 (linear)
                 u16* __restrict__ hbn,             // [2048][1024] bf16 out
                 u32* __restrict__ cnt) {
  constexpr bool P_STAGE = (PH & 1) != 0;
  constexpr bool P_MFMA  = (PH & 2) != 0;
  constexpr bool P_GATE  = (PH & 4) != 0;
  constexpr bool P_SYNC  = (PH & 8) != 0;

  __shared__ char hA[32 * 1024];       // staged h(s), swizzled (elided if unused)
  __shared__ float zxP[8][16][16];     // per-wave partial z

  const int wg = blockIdx.x;
  const int u0 = wg << 4;
  const int tid = threadIdx.x;
  const int lane = tid & 63;
  const int wv = tid >> 6;
  const int ln = lane & 15, khq = lane >> 4;
  const int cg = wv & 3, kh2 = wv >> 2;

  const int g = ln & 3;                // gate index (i,f,cc,o)
  const int unit = u0 + cg * 4 + (ln >> 2);

  // ---- Wh preload: 16 x s16x8 = 64 VGPRs, pinned live ----
  s16x8 bW[16];
  if constexpr (P_MFMA) {
    const u16* wrow = Wht + (size_t)(g * 1024 + unit) * 1024 + kh2 * 512 + khq * 8;
#pragma unroll
    for (int kt = 0; kt < 16; ++kt)
      bW[kt] = *(const s16x8*)(wrow + kt * 32);
#pragma unroll
    for (int kt = 0; kt < 16; ++kt)
      asm volatile("" : "+v"(bW[kt]));
  }

  // per-lane state (meaningful in waves 0-3 only)
  float cellR[4] = {}, holdR[4] = {}, xgr[4] = {};
  u64 mA[4] = {}, mB[4] = {};
  float bn_s = 0.f, bn_b = 0.f;
  const size_t bstride = (size_t)128 * 4096;
  const float* xbase = xg + (size_t)(khq * 4) * bstride + g * 1024 + unit;
  if constexpr (P_GATE) {
    if (kh2 == 0) {
      bn_s = gamma[unit] * rsqrtf(mvar[unit] + 1e-3f);
      bn_b = beta[unit] - mmean[unit] * bn_s;
#pragma unroll
      for (int r = 0; r < 4; ++r) {
        int batch = khq * 4 + r;
        cellR[r] = encc[batch * 1024 + unit];
        holdR[r] = ench[batch * 1024 + unit];
        mA[r] = maskb[batch * 2];
        mB[r] = maskb[batch * 2 + 1];
      }
      // initial publish of h(0) into parity-0 buffer
#pragma unroll
      for (int r = 0; r < 4; ++r) {
        u32 w = (u32)f2bf(holdR[r]);
        u32 pw = (u32)__shfl_xor((int)w, 4);
        if ((ln & 7) == 0) {
          int batch = khq * 4 + r;
          AT_ST((u32*)((char*)hbuf32 + batch * 2048 + unit * 2), (w & 0xFFFFu) | (pw << 16));
        }
      }
#pragma unroll
      for (int r = 0; r < 4; ++r) xgr[r] = xbase[r * bstride];   // xg(0) prefetch
    }
    asm volatile("s_waitcnt vmcnt(0)" ::: "memory");
  }
  __syncthreads();
  if constexpr (P_SYNC) {
    if (tid == 0) {
      int oldv = (int)__hip_atomic_fetch_add(cnt, 1, __ATOMIC_RELAXED, __HIP_MEMORY_SCOPE_AGENT);
      if (oldv != 63) {
        int c = 0;
        while (AT_LD((const u32*)cnt) < 64u) {
          __builtin_amdgcn_s_sleep(1);
          if (++c > (1 << 18)) break;
        }
      }
    }
    __syncthreads();
  }

  for (int s = 0; s < STEPS; ++s) {
    if constexpr (P_STAGE) {
      // ---- stage h(s): 8 back-to-back uncached loads, one waitcnt ----
      u64 st[8];
      const u64* base = (const u64*)((const char*)hbuf32 + (s & 1) * 32768) + tid;
#pragma unroll
      for (int k = 0; k < 8; ++k) {
        const u64* pp = base + k * 512;
        asm volatile("global_load_dwordx2 %0, %1, off sc0 sc1" : "=v"(st[k]) : "v"(pp));
      }
      asm volatile("s_waitcnt vmcnt(0)" ::: "memory");
      __builtin_amdgcn_sched_barrier(0);
#pragma unroll
      for (int k = 0; k < 8; ++k)
        *(u64*)(hA + swzB((tid + k * 512) * 8)) = st[k];
      if constexpr (!P_MFMA) {
        u32 dv = *(const u32*)(hA + ((tid * 8) & 32760));  // keep writes live
        asm volatile("" :: "v"(dv));
      }
      __syncthreads();                           // (A) hA ready
    }

    if constexpr (P_MFMA) {
      // ---- 16 MFMA over this wave's 512-k slice, 2 chains ----
      f32x4 acc0 = {0.f, 0.f, 0.f, 0.f};
      f32x4 acc1 = {0.f, 0.f, 0.f, 0.f};
#pragma unroll
      for (int kt = 0; kt < 16; kt += 2) {
        s16x8 a0 = *(const s16x8*)(hA + swzB(ln * 2048 + kh2 * 1024 + kt * 64 + khq * 16));
        acc0 = __builtin_amdgcn_mfma_f32_16x16x32_bf16(a0, bW[kt], acc0, 0, 0, 0);
        s16x8 a1 = *(const s16x8*)(hA + swzB(ln * 2048 + kh2 * 1024 + (kt + 1) * 64 + khq * 16));
        acc1 = __builtin_amdgcn_mfma_f32_16x16x32_bf16(a1, bW[kt + 1], acc1, 0, 0, 0);
      }
      f32x4 accs = acc0 + acc1;
      if constexpr (!P_GATE) {
        asm volatile("" :: "v"(accs[0]), "v"(accs[1]), "v"(accs[2]), "v"(accs[3]));
      }
#pragma unroll
      for (int r = 0; r < 4; ++r) zxP[wv][khq * 4 + r][ln] = accs[r];
      __syncthreads();                           // (B2) partials ready
    }

    if constexpr (P_GATE) {
      if (kh2 == 0) {
        // ---- combine k-halves + gates (in-wave) + publish ----
        u16 hbb[4], hbnb[4];
#pragma unroll
        for (int r = 0; r < 4; ++r) {
          int batch = khq * 4 + r;
          float z = zxP[cg][batch][ln] + zxP[cg + 4][batch][ln] + xgr[r];
          float sig = 1.f / (1.f + __expf(-z));
          float val = (g == 2) ? fmaxf(z, 0.f) : sig;
          float v1 = __shfl_xor(val, 1);
          float v2 = __shfl_xor(val, 2);
          float v3 = __shfl_xor(val, 3);
          float cnew = v1 * cellR[r] + val * v2;   // f*c + i*cc (g==0 view)
          float hnew = v3 * fmaxf(cnew, 0.f);
          u64 mm = (s < 64) ? mA[r] : mB[r];
          if (!((mm >> (s & 63)) & 1)) { cnew = cellR[r]; hnew = holdR[r]; }
          cellR[r] = cnew;
          holdR[r] = hnew;
          hbb[r] = f2bf(hnew);
          hbnb[r] = f2bf(hnew * bn_s + bn_b);
        }
#pragma unroll
        for (int r = 0; r < 4; ++r) {
          u32 w = (u32)hbb[r] | ((u32)hbnb[r] << 16);
          u32 pw = (u32)__shfl_xor((int)w, 4);
          if ((ln & 7) == 0) {
            int batch = khq * 4 + r;
            u32 hpair = (w & 0xFFFFu) | ((pw & 0xFFFFu) << 16);
            u32 bnpair = (w >> 16) | (pw & 0xFFFF0000u);
            if (s < 127) {
              int B = batch * 2048 + unit * 2;
              AT_ST((u32*)((char*)hbuf32 + ((s + 1) & 1) * 32768 + B), hpair);
            }
            *(u32*)((char*)hbn + (size_t)(batch * 128 + s) * 2048 + unit * 2) = bnpair;
          }
        }
      }
    }

    if (s < STEPS - 1) {
      if constexpr (P_SYNC) {
        if constexpr (P_GATE)
          asm volatile("s_waitcnt vmcnt(0)" ::: "memory");
        __syncthreads();                         // (B3) publishes drained
        int oldv = -1;
        if (tid == 0)
          oldv = (int)__hip_atomic_fetch_add(cnt, 1, __ATOMIC_RELAXED, __HIP_MEMORY_SCOPE_AGENT);
        if constexpr (P_GATE) {
          if (kh2 == 0) {                        // xg(s+1) prefetch overlaps poll
            const float* xb = xbase + (size_t)(s + 1) * 4096;
#pragma unroll
            for (int r = 0; r < 4; ++r) xgr[r] = xb[r * bstride];
          }
        }
        if (tid == 0) {
          const u32 target = (u32)(s + 2) * 64u;
          if (oldv != (int)target - 1) {
            int c = 0;
            while (AT_LD((const u32*)cnt) < target) {
              __builtin_amdgcn_s_sleep(1);
              if (++c > (1 << 18)) break;
            }
          }
        }
        __syncthreads();                         // (C) release
      }
    }
  }
}

// ---------- softmax finish ----------

__global__ void rcp_kernel(float* rs) {
  int i = blockIdx.x * 256 + threadIdx.x;   // 2048 threads
  rs[i] = 1.0f / rs[i];
}

__global__ void scale_kernel(float* __restrict__ out, const float* __restrict__ rinv) {
  const int total4 = 16384000;              // 65,536,000 / 4
  for (int i = blockIdx.x * 256 + threadIdx.x; i < total4; i += gridDim.x * 256) {
    float4* p = (float4*)out + i;
    float4 v = *p;
    int row = i / 8000;                     // 8000 float4 per row
    float sF = rinv[row];
    v.x *= sF; v.y *= sF; v.z *= sF; v.w *= sF;
    *p = v;
  }
}

// ---------- launch ----------

extern "C" void kernel_launch(void* const* d_in, const int* in_sizes, int n_in,
                              void* d_out, int out_size, void* d_ws, size_t ws_size,
                              hipStream_t stream) {
  (void)in_sizes; (void)n_in; (void)out_size;
  const int*   inputs = (const int*)d_in[0];
  const float* ench   = (const float*)d_in[1];
  const float* encc   = (const float*)d_in[2];
  const float* emb    = (const float*)d_in[3];
  const float* Wx     = (const float*)d_in[4];
  const float* Wh     = (const float*)d_in[5];
  const float* bb     = (const float*)d_in[6];
  const float* gamma  = (const float*)d_in[7];
  const float* beta   = (const float*)d_in[8];
  const float* mmean  = (const float*)d_in[9];
  const float* mvar   = (const float*)d_in[10];
  const float* W1     = (const float*)d_in[11];
  const float* b1     = (const float*)d_in[12];
  const float* W2     = (const float*)d_in[13];
  const float* b2     = (const float*)d_in[14];
  float* out = (float*)d_out;

  char* p = (char*)d_ws;
  u32*   cnt    = (u32*)(p + 0);            // real barrier counter
  u32*   cntS   = (u32*)(p + 128);          // V_SYNC counter
  u32*   cntT   = (u32*)(p + 192);          // V_STAGE counter
  float* rowsum = (float*)(p + 1024);       // 2048 floats; memset covers [0,9216)
  u64*   maskb  = (u64*)(p + 10240);        // 256B, written by mask_kernel
  u32*   hbuf32 = (u32*)(p + 16384);        // 64KB (2 x 32KB parity tiles)
  size_t off = 81920;
  u16*   xbf  = (u16*)(p + off);     off += (size_t)2048 * 512 * 2;     // 2MB
  u16*   Wxt  = (u16*)(p + off);     off += (size_t)4096 * 512 * 2;     // 4MB
  u16*   Wht  = (u16*)(p + off);     off += (size_t)4096 * 1024 * 2;    // 8MB
  u16*   W1t  = (u16*)(p + off);     off += (size_t)1024 * 1024 * 2;    // 2MB
  u16*   W2t  = (u16*)(p + off);     off += (size_t)32000 * 1024 * 2;   // 64MB
  float* xg   = (float*)(p + off);   off += (size_t)2048 * 4096 * 4;    // 32MB
  u16*   hbn  = (u16*)(p + off);     off += (size_t)2048 * 1024 * 2;    // 4MB
  u16*   d1   = (u16*)(p + off);     off += (size_t)2048 * 1024 * 2;    // 4MB
  if (ws_size < off) return;  // insufficient scratch; avoid OOB

  hipMemsetAsync(d_ws, 0, 9216, stream);  // cnt/cntS/cntT + rowsum

  embed_kernel<<<512, 256, 0, stream>>>(inputs, emb, xbf);
  mask_kernel<<<1, 64, 0, stream>>>(inputs, maskb);
  transpose_bf16<<<(512 / 32) * (4096 / 32), 256, 0, stream>>>(Wx, Wxt, 512, 4096);
  transpose_bf16<<<(1024 / 32) * (4096 / 32), 256, 0, stream>>>(Wh, Wht, 1024, 4096);
  transpose_bf16<<<(1024 / 32) * (1024 / 32), 256, 0, stream>>>(W1, W1t, 1024, 1024);
  transpose_bf16<<<(1024 / 32) * (32000 / 32), 256, 0, stream>>>(W2, W2t, 1024, 32000);

  gemm_bf16<0><<<16 * 32, 256, 0, stream>>>(xbf, Wxt, bb, xg, nullptr, 2048, 4096, 512);

  lstm_kernel<128, 15><<<64, 512, 0, stream>>>(xg, Wht, maskb, ench, encc, gamma, beta,
                                               mmean, mvar, hbuf32, hbn, cnt);

  gemm_bf16<1><<<16 * 8, 256, 0, stream>>>(hbn, W1t, b1, d1, nullptr, 2048, 1024, 1024);
  gemm_bf16<2><<<16 * 250, 256, 0, stream>>>(d1, W2t, b2, out, rowsum, 2048, 32000, 1024);

  rcp_kernel<<<8, 256, 0, stream>>>(rowsum);
  scale_kernel<<<2048, 256, 0, stream>>>(out, rowsum);

  // ---- diagnostics (read-only on real buffers; own counters; no d_out writes)
  // V_SYNC: sync skeleton x512 steps. V_STAGE: stage+sync x256 steps.
  // Identify rows by LDS_Block_Size (tiny / ~33KB) + Dispatch_Id (after real).
  lstm_kernel<512, 8><<<64, 512, 0, stream>>>(xg, Wht, maskb, ench, encc, gamma, beta,
                                              mmean, mvar, hbuf32, hbn, cntS);
  lstm_kernel<256, 9><<<64, 512, 0, stream>>>(xg, Wht, maskb, ench, encc, gamma, beta,
                                              mmean, mvar, hbuf32, hbn, cntT);
}

// Round 9
// 1068.765 us; speedup vs baseline: 1.9354x; 1.9354x over previous
//
#include <hip/hip_runtime.h>
#include <hip/hip_bf16.h>
#include <stdint.h>

typedef unsigned short u16;
typedef unsigned int u32;
typedef unsigned long long u64;
typedef __attribute__((ext_vector_type(4))) float f32x4;
typedef __attribute__((ext_vector_type(8))) short s16x8;
typedef __attribute__((ext_vector_type(4))) unsigned int u32x4;

#define AT_LD(p)    __hip_atomic_load((p), __ATOMIC_RELAXED, __HIP_MEMORY_SCOPE_AGENT)
#define AT_ST(p, v) __hip_atomic_store((p), (v), __ATOMIC_RELAXED, __HIP_MEMORY_SCOPE_AGENT)
#define AT_FAA(p)   __hip_atomic_fetch_add((p), 1u, __ATOMIC_RELAXED, __HIP_MEMORY_SCOPE_AGENT)

// ---------- helpers ----------

static __device__ __forceinline__ u16 f2bf(float f) {
  union { float f; unsigned u; } v; v.f = f;
  unsigned r = v.u + 0x7FFFu + ((v.u >> 16) & 1u);
  return (u16)(r >> 16);
}

static __device__ __forceinline__ void gload_lds16(const void* g, void* l) {
  __builtin_amdgcn_global_load_lds(
      (const __attribute__((address_space(1))) unsigned int*)(uintptr_t)g,
      (__attribute__((address_space(3))) unsigned int*)(uintptr_t)l,
      16, 0, 0);
}

// ---------- pre-pass kernels ----------

__global__ void embed_kernel(const int* __restrict__ inputs,
                             const float* __restrict__ emb,
                             u16* __restrict__ xbf) {
  int i = blockIdx.x * 256 + threadIdx.x;   // 131072 threads
  int row = i >> 6;
  int e0 = (i & 63) << 3;
  int tok = inputs[row];
  const float* src = emb + (size_t)tok * 512 + e0;
  s16x8 o;
#pragma unroll
  for (int j = 0; j < 8; ++j) o[j] = (short)f2bf(src[j]);
  *(s16x8*)(xbf + (size_t)row * 512 + e0) = o;
}

// bit-pack mask: maskb[b*2+h] bit j = (inputs[b*128 + h*64 + j] != 0)
__global__ void mask_kernel(const int* __restrict__ inputs, u64* __restrict__ mb) {
  int t = threadIdx.x;
  if (t < 32) {
    int b = t >> 1, h = t & 1;
    u64 m = 0;
    for (int j = 0; j < 64; ++j)
      m |= (u64)(inputs[b * 128 + h * 64 + j] != 0) << j;
    mb[t] = m;
  }
}

// Wt[n][k] = bf16(W[k][n]); K,N multiples of 32
__global__ void transpose_bf16(const float* __restrict__ W, u16* __restrict__ Wt,
                               int K, int N) {
  __shared__ float t[32][33];
  int ntn = N >> 5;
  int tn = blockIdx.x % ntn, tk = blockIdx.x / ntn;
  int n0 = tn << 5, k0 = tk << 5;
  int tx = threadIdx.x & 31, ty = threadIdx.x >> 5;  // ty 0..7
#pragma unroll
  for (int j = 0; j < 4; ++j) {
    int k = ty * 4 + j;
    t[k][tx] = W[(size_t)(k0 + k) * N + n0 + tx];
  }
  __syncthreads();
#pragma unroll
  for (int j = 0; j < 4; ++j) {
    int n = ty * 4 + j;
    Wt[(size_t)(n0 + n) * K + k0 + tx] = f2bf(t[tx][n]);
  }
}

// ---------- m97-style bf16 GEMM, 128x128 tile, BK=32 ----------
// MODE 0: C=f32, store acc+bias          (xg)
// MODE 1: C=bf16, store relu(acc+bias)   (d1)
// MODE 2: C=f32, store exp(acc+bias), atomicAdd row sums (logits->exp)
template <int MODE>
__global__ __launch_bounds__(256)
void gemm_bf16(const u16* __restrict__ A, const u16* __restrict__ Bt,
               const float* __restrict__ bias, void* __restrict__ Cptr,
               float* __restrict__ rowsum, int M, int N, int K) {
  (void)M;
  __shared__ u16 sA[128 * 32];
  __shared__ u16 sB[128 * 32];
  const int nbn = N >> 7;
  const int nwg = gridDim.x;
  int bid = blockIdx.x;
  int q = nwg >> 3;                         // grids are multiples of 8
  int swz = (bid & 7) * q + (bid >> 3);     // XCD-aware swizzle (bijective)
  int bm = swz / nbn, bn = swz % nbn;
  const int brow = bm << 7, bcol = bn << 7;

  const int tid = threadIdx.x;
  const int lane = tid & 63;
  const int wv = tid >> 6;
  const int wr = (wv >> 1) * 64, wc = (wv & 1) * 64;
  const int ln = lane & 15, kh = lane >> 4;

  const int srow = tid >> 2;                // 0..63
  const int kch = (tid & 3) << 3;           // 0,8,16,24 (elements)

  f32x4 acc[4][4] = {};

  const int nk = K >> 5;
  const u16* Abase = A + (size_t)(brow + srow) * K + kch;
  const u16* Bbase = Bt + (size_t)(bcol + srow) * K + kch;
  const size_t rstride = (size_t)64 * K;
  u16* lA = sA + srow * 32 + kch;
  u16* lB = sB + srow * 32 + kch;

  for (int kt = 0; kt < nk; ++kt) {
    const int k0 = kt << 5;
    gload_lds16(Abase + k0, lA);
    gload_lds16(Abase + rstride + k0, lA + 64 * 32);
    gload_lds16(Bbase + k0, lB);
    gload_lds16(Bbase + rstride + k0, lB + 64 * 32);
    __syncthreads();
    s16x8 aF[4], bF[4];
#pragma unroll
    for (int m = 0; m < 4; ++m)
      aF[m] = *(const s16x8*)(sA + (wr + m * 16 + ln) * 32 + kh * 8);
#pragma unroll
    for (int n = 0; n < 4; ++n)
      bF[n] = *(const s16x8*)(sB + (wc + n * 16 + ln) * 32 + kh * 8);
#pragma unroll
    for (int m = 0; m < 4; ++m)
#pragma unroll
      for (int n = 0; n < 4; ++n)
        acc[m][n] = __builtin_amdgcn_mfma_f32_16x16x32_bf16(aF[m], bF[n], acc[m][n], 0, 0, 0);
    __syncthreads();
  }

  const int browq = brow + wr;
  const int bcolq = bcol + wc;

  if (MODE == 1) {
    u16* O = (u16*)Cptr;
#pragma unroll
    for (int n = 0; n < 4; ++n) {
      int gcol = bcolq + n * 16 + ln;
      float bv = bias[gcol];
#pragma unroll
      for (int m = 0; m < 4; ++m)
#pragma unroll
        for (int r = 0; r < 4; ++r) {
          int grow = browq + m * 16 + kh * 4 + r;
          float v = fmaxf(acc[m][n][r] + bv, 0.f);
          O[(size_t)grow * N + gcol] = f2bf(v);
        }
    }
  } else {
    float* O = (float*)Cptr;
    float rs[4][4] = {};
#pragma unroll
    for (int n = 0; n < 4; ++n) {
      int gcol = bcolq + n * 16 + ln;
      float bv = bias[gcol];
#pragma unroll
      for (int m = 0; m < 4; ++m)
#pragma unroll
        for (int r = 0; r < 4; ++r) {
          int grow = browq + m * 16 + kh * 4 + r;
          float v = acc[m][n][r] + bv;
          if (MODE == 2) { v = __expf(v); rs[m][r] += v; }
          O[(size_t)grow * N + gcol] = v;
        }
    }
    if (MODE == 2) {
#pragma unroll
      for (int m = 0; m < 4; ++m)
#pragma unroll
        for (int r = 0; r < 4; ++r) {
          float v = rs[m][r];
          v += __shfl_xor(v, 1);
          v += __shfl_xor(v, 2);
          v += __shfl_xor(v, 4);
          v += __shfl_xor(v, 8);
          if (ln == 0) atomicAdd(&rowsum[browq + m * 16 + kh * 4 + r], v);
        }
    }
  }
}

// ---------- persistent LSTM: 64 WGs x 512 threads, tree barrier ----------
// Sync: leaf counters (8 WGs each, 256B apart) -> root counter -> poll root.
// Measured decomposition (r8): flat sync 1.19us/step, stage 0.6, rest 2.2.
// LDS h tile: padded rows (2064B pitch) -> ds_read_b128 with imm offsets,
// 2-way bank aliasing only (free). hbn stores deferred past the arrive.
__global__ __launch_bounds__(512, 1)
void lstm_kernel(const float* __restrict__ xg,      // [2048][4096] f32
                 const u16* __restrict__ Wht,       // [4096][1024] bf16 (n-major)
                 const u64* __restrict__ maskb,     // [16][2] bitmask
                 const float* __restrict__ ench, const float* __restrict__ encc,
                 const float* __restrict__ gamma, const float* __restrict__ beta,
                 const float* __restrict__ mmean, const float* __restrict__ mvar,
                 u32* __restrict__ hbuf32,          // [2][16][512] u32 (linear)
                 u16* __restrict__ hbn,             // [2048][1024] bf16 out
                 u32* __restrict__ sync) {          // leaves @ +64*u32 each, root @ +512
  __shared__ char hA[16 * 2064];       // padded h(s) tile, 33024B
  __shared__ float zxP[8][16][16];     // per-wave partial z

  const int wg = blockIdx.x;
  const int u0 = wg << 4;
  const int tid = threadIdx.x;
  const int lane = tid & 63;
  const int wv = tid >> 6;
  const int ln = lane & 15, khq = lane >> 4;
  const int cg = wv & 3, kh2 = wv >> 2;

  const int g = ln & 3;                // gate index (i,f,cc,o)
  const int unit = u0 + cg * 4 + (ln >> 2);

  u32* leaf = sync + (wg >> 3) * 64;
  u32* root = sync + 512;

  // ---- Wh preload: 16 x s16x8 = 64 VGPRs, pinned live ----
  s16x8 bW[16];
  {
    const u16* wrow = Wht + (size_t)(g * 1024 + unit) * 1024 + kh2 * 512 + khq * 8;
#pragma unroll
    for (int kt = 0; kt < 16; ++kt)
      bW[kt] = *(const s16x8*)(wrow + kt * 32);
#pragma unroll
    for (int kt = 0; kt < 16; ++kt)
      asm volatile("" : "+v"(bW[kt]));
  }

  // per-lane state (meaningful in waves 0-3, g==0 lanes)
  float cellR[4] = {}, holdR[4] = {}, xgr[4] = {};
  u64 mA[4] = {}, mB[4] = {};
  float bn_s = 0.f, bn_b = 0.f;
  const size_t bstride = (size_t)128 * 4096;
  const float* xbase = xg + (size_t)(khq * 4) * bstride + g * 1024 + unit;
  if (kh2 == 0) {
    bn_s = gamma[unit] * rsqrtf(mvar[unit] + 1e-3f);
    bn_b = beta[unit] - mmean[unit] * bn_s;
#pragma unroll
    for (int r = 0; r < 4; ++r) {
      int batch = khq * 4 + r;
      cellR[r] = encc[batch * 1024 + unit];
      holdR[r] = ench[batch * 1024 + unit];
      mA[r] = maskb[batch * 2];
      mB[r] = maskb[batch * 2 + 1];
    }
    // initial publish of h(0) into parity-0 buffer
#pragma unroll
    for (int r = 0; r < 4; ++r) {
      u32 w = (u32)f2bf(holdR[r]);
      u32 pw = (u32)__shfl_xor((int)w, 4);
      if ((ln & 7) == 0) {
        int batch = khq * 4 + r;
        AT_ST((u32*)((char*)hbuf32 + batch * 2048 + unit * 2), (w & 0xFFFFu) | (pw << 16));
      }
    }
#pragma unroll
    for (int r = 0; r < 4; ++r) xgr[r] = xbase[r * bstride];   // xg(0) prefetch
  }
  asm volatile("s_waitcnt vmcnt(0)" ::: "memory");
  __syncthreads();
  int syncno = 1;
  if (tid == 0) {
    bool last = false;
    u32 lo = AT_FAA(leaf);
    if (lo == (u32)(syncno * 8 - 1)) {
      u32 ro = AT_FAA(root);
      last = (ro == (u32)(syncno * 8 - 1));
    }
    if (!last) {
      int c = 0;
      while (AT_LD(root) < (u32)(syncno * 8)) {
        __builtin_amdgcn_s_sleep(1);
        if (++c > (1 << 18)) break;
      }
    }
  }
  __syncthreads();

  for (int s = 0; s < 128; ++s) {
    // ---- stage h(s): 4 x dwordx4 uncached loads -> padded LDS rows ----
    {
      u32x4 st[4];
      const char* base = (const char*)hbuf32 + (s & 1) * 32768 + tid * 16;
#pragma unroll
      for (int k = 0; k < 4; ++k) {
        const char* pp = base + k * 8192;
        asm volatile("global_load_dwordx4 %0, %1, off sc0 sc1" : "=v"(st[k]) : "v"(pp));
      }
      asm volatile("s_waitcnt vmcnt(0)" ::: "memory");
      __builtin_amdgcn_sched_barrier(0);
#pragma unroll
      for (int k = 0; k < 4; ++k) {
        int idx = tid + k * 512;               // 16B chunk index, 0..2047
        int row = idx >> 7;                    // batch
        int col = (idx & 127) * 16;            // byte col in row
        *(u32x4*)(hA + row * 2064 + col) = st[k];
      }
    }
    __syncthreads();                           // (A) hA ready

    // ---- 16 MFMA over this wave's 512-k slice, 2 chains ----
    f32x4 acc0 = {0.f, 0.f, 0.f, 0.f};
    f32x4 acc1 = {0.f, 0.f, 0.f, 0.f};
    {
      const char* arow = hA + ln * 2064 + kh2 * 1024 + khq * 16;
#pragma unroll
      for (int kt = 0; kt < 16; kt += 2) {
        s16x8 a0 = *(const s16x8*)(arow + kt * 64);
        acc0 = __builtin_amdgcn_mfma_f32_16x16x32_bf16(a0, bW[kt], acc0, 0, 0, 0);
        s16x8 a1 = *(const s16x8*)(arow + (kt + 1) * 64);
        acc1 = __builtin_amdgcn_mfma_f32_16x16x32_bf16(a1, bW[kt + 1], acc1, 0, 0, 0);
      }
    }
    f32x4 accs = acc0 + acc1;
#pragma unroll
    for (int r = 0; r < 4; ++r) zxP[wv][khq * 4 + r][ln] = accs[r];
    __syncthreads();                           // (B2) partials ready

    u32 bnpair[4];
    if (kh2 == 0) {
      // ---- combine k-halves + gates (in-wave) + publish h(s+1) ----
      u16 hbb[4], hbnb[4];
#pragma unroll
      for (int r = 0; r < 4; ++r) {
        int batch = khq * 4 + r;
        float z = zxP[cg][batch][ln] + zxP[cg + 4][batch][ln] + xgr[r];
        float sig = 1.f / (1.f + __expf(-z));
        float val = (g == 2) ? fmaxf(z, 0.f) : sig;
        float v1 = __shfl_xor(val, 1);
        float v2 = __shfl_xor(val, 2);
        float v3 = __shfl_xor(val, 3);
        float cnew = v1 * cellR[r] + val * v2;   // f*c + i*cc (g==0 view)
        float hnew = v3 * fmaxf(cnew, 0.f);
        u64 mm = (s < 64) ? mA[r] : mB[r];
        if (!((mm >> (s & 63)) & 1)) { cnew = cellR[r]; hnew = holdR[r]; }
        cellR[r] = cnew;
        holdR[r] = hnew;
        hbb[r] = f2bf(hnew);
        hbnb[r] = f2bf(hnew * bn_s + bn_b);
      }
#pragma unroll
      for (int r = 0; r < 4; ++r) {
        u32 w = (u32)hbb[r] | ((u32)hbnb[r] << 16);
        u32 pw = (u32)__shfl_xor((int)w, 4);
        u32 hpair = (w & 0xFFFFu) | ((pw & 0xFFFFu) << 16);
        bnpair[r] = (w >> 16) | (pw & 0xFFFF0000u);
        if (s < 127 && (ln & 7) == 0) {
          int batch = khq * 4 + r;
          AT_ST((u32*)((char*)hbuf32 + ((s + 1) & 1) * 32768 + batch * 2048 + unit * 2), hpair);
        }
      }
    }

    if (s < 127) {
      asm volatile("s_waitcnt vmcnt(0)" ::: "memory");   // drain h publishes only
      __syncthreads();                         // (B3)
      ++syncno;
      bool last = false;
      if (tid == 0) {
        u32 lo = AT_FAA(leaf);
        if (lo == (u32)(syncno * 8 - 1)) {
          u32 ro = AT_FAA(root);
          last = (ro == (u32)(syncno * 8 - 1));
        }
      }
      if (kh2 == 0) {
        // deferred hbn stores + xg(s+1) prefetch overlap the poll
        if ((ln & 7) == 0) {
#pragma unroll
          for (int r = 0; r < 4; ++r) {
            int batch = khq * 4 + r;
            *(u32*)((char*)hbn + (size_t)(batch * 128 + s) * 2048 + unit * 2) = bnpair[r];
          }
        }
        const float* xb = xbase + (size_t)(s + 1) * 4096;
#pragma unroll
        for (int r = 0; r < 4; ++r) xgr[r] = xb[r * bstride];
      }
      if (tid == 0 && !last) {
        int c = 0;
        while (AT_LD(root) < (u32)(syncno * 8)) {
          __builtin_amdgcn_s_sleep(1);
          if (++c > (1 << 18)) break;
        }
      }
      __syncthreads();                         // (C) release
    } else if (kh2 == 0 && (ln & 7) == 0) {
      // s == 127: final hbn stores
#pragma unroll
      for (int r = 0; r < 4; ++r) {
        int batch = khq * 4 + r;
        *(u32*)((char*)hbn + (size_t)(batch * 128 + s) * 2048 + unit * 2) = bnpair[r];
      }
    }
  }
}

// ---------- softmax finish ----------

__global__ void rcp_kernel(float* rs) {
  int i = blockIdx.x * 256 + threadIdx.x;   // 2048 threads
  rs[i] = 1.0f / rs[i];
}

__global__ void scale_kernel(float* __restrict__ out, const float* __restrict__ rinv) {
  const int total4 = 16384000;              // 65,536,000 / 4
  for (int i = blockIdx.x * 256 + threadIdx.x; i < total4; i += gridDim.x * 256) {
    float4* p = (float4*)out + i;
    float4 v = *p;
    int row = i / 8000;                     // 8000 float4 per row
    float sF = rinv[row];
    v.x *= sF; v.y *= sF; v.z *= sF; v.w *= sF;
    *p = v;
  }
}

// ---------- launch ----------

extern "C" void kernel_launch(void* const* d_in, const int* in_sizes, int n_in,
                              void* d_out, int out_size, void* d_ws, size_t ws_size,
                              hipStream_t stream) {
  (void)in_sizes; (void)n_in; (void)out_size;
  const int*   inputs = (const int*)d_in[0];
  const float* ench   = (const float*)d_in[1];
  const float* encc   = (const float*)d_in[2];
  const float* emb    = (const float*)d_in[3];
  const float* Wx     = (const float*)d_in[4];
  const float* Wh     = (const float*)d_in[5];
  const float* bb     = (const float*)d_in[6];
  const float* gamma  = (const float*)d_in[7];
  const float* beta   = (const float*)d_in[8];
  const float* mmean  = (const float*)d_in[9];
  const float* mvar   = (const float*)d_in[10];
  const float* W1     = (const float*)d_in[11];
  const float* b1     = (const float*)d_in[12];
  const float* W2     = (const float*)d_in[13];
  const float* b2     = (const float*)d_in[14];
  float* out = (float*)d_out;

  char* p = (char*)d_ws;
  u32*   sync   = (u32*)(p + 0);            // leaves @ +0..+1792 (256B apart), root @ +2048
  float* rowsum = (float*)(p + 4096);       // 2048 floats -> [4096, 12288)
  u64*   maskb  = (u64*)(p + 12288);        // 256B, written by mask_kernel
  u32*   hbuf32 = (u32*)(p + 16384);        // 64KB (2 x 32KB parity tiles)
  size_t off = 81920;
  u16*   xbf  = (u16*)(p + off);     off += (size_t)2048 * 512 * 2;     // 2MB
  u16*   Wxt  = (u16*)(p + off);     off += (size_t)4096 * 512 * 2;     // 4MB
  u16*   Wht  = (u16*)(p + off);     off += (size_t)4096 * 1024 * 2;    // 8MB
  u16*   W1t  = (u16*)(p + off);     off += (size_t)1024 * 1024 * 2;    // 2MB
  u16*   W2t  = (u16*)(p + off);     off += (size_t)32000 * 1024 * 2;   // 64MB
  float* xg   = (float*)(p + off);   off += (size_t)2048 * 4096 * 4;    // 32MB
  u16*   hbn  = (u16*)(p + off);     off += (size_t)2048 * 1024 * 2;    // 4MB
  u16*   d1   = (u16*)(p + off);     off += (size_t)2048 * 1024 * 2;    // 4MB
  if (ws_size < off) return;  // insufficient scratch; avoid OOB

  hipMemsetAsync(d_ws, 0, 16384, stream);  // sync counters + rowsum

  embed_kernel<<<512, 256, 0, stream>>>(inputs, emb, xbf);
  mask_kernel<<<1, 64, 0, stream>>>(inputs, maskb);
  transpose_bf16<<<(512 / 32) * (4096 / 32), 256, 0, stream>>>(Wx, Wxt, 512, 4096);
  transpose_bf16<<<(1024 / 32) * (4096 / 32), 256, 0, stream>>>(Wh, Wht, 1024, 4096);
  transpose_bf16<<<(1024 / 32) * (1024 / 32), 256, 0, stream>>>(W1, W1t, 1024, 1024);
  transpose_bf16<<<(1024 / 32) * (32000 / 32), 256, 0, stream>>>(W2, W2t, 1024, 32000);

  gemm_bf16<0><<<16 * 32, 256, 0, stream>>>(xbf, Wxt, bb, xg, nullptr, 2048, 4096, 512);

  lstm_kernel<<<64, 512, 0, stream>>>(xg, Wht, maskb, ench, encc, gamma, beta,
                                      mmean, mvar, hbuf32, hbn, sync);

  gemm_bf16<1><<<16 * 8, 256, 0, stream>>>(hbn, W1t, b1, d1, nullptr, 2048, 1024, 1024);
  gemm_bf16<2><<<16 * 250, 256, 0, stream>>>(d1, W2t, b2, out, rowsum, 2048, 32000, 1024);

  rcp_kernel<<<8, 256, 0, stream>>>(rowsum);
  scale_kernel<<<2048, 256, 0, stream>>>(out, rowsum);
}

// Round 10
// 978.493 us; speedup vs baseline: 2.1139x; 1.0923x over previous
//
#include <hip/hip_runtime.h>
#include <hip/hip_bf16.h>
#include <stdint.h>

typedef unsigned short u16;
typedef unsigned int u32;
typedef unsigned long long u64;
typedef __attribute__((ext_vector_type(4))) float f32x4;
typedef __attribute__((ext_vector_type(8))) short s16x8;

#define AT_LD(p)    __hip_atomic_load((p), __ATOMIC_RELAXED, __HIP_MEMORY_SCOPE_AGENT)
#define AT_ST(p, v) __hip_atomic_store((p), (v), __ATOMIC_RELAXED, __HIP_MEMORY_SCOPE_AGENT)
#define AT_FAA(p)   __hip_atomic_fetch_add((p), 1u, __ATOMIC_RELAXED, __HIP_MEMORY_SCOPE_AGENT)

// ---------- helpers ----------

static __device__ __forceinline__ u16 f2bf(float f) {
  union { float f; unsigned u; } v; v.f = f;
  unsigned r = v.u + 0x7FFFu + ((v.u >> 16) & 1u);
  return (u16)(r >> 16);
}

static __device__ __forceinline__ void gload_lds16(const void* g, void* l) {
  __builtin_amdgcn_global_load_lds(
      (const __attribute__((address_space(1))) unsigned int*)(uintptr_t)g,
      (__attribute__((address_space(3))) unsigned int*)(uintptr_t)l,
      16, 0, 0);
}

// bank-balancing swizzle for the 32KB h tile in LDS (r6/r7 proven).
static __device__ __forceinline__ int swzB(int B) {
  int pos = (B >> 4) & 127;
  int row = (B >> 11) & 15;
  int slot = (pos ^ row ^ (pos >> 3)) & 7;
  int npos = (pos & 0x78) | slot;
  return (B & ~0x7F0) | (npos << 4);
}

// ---------- pre-pass kernels ----------

__global__ void embed_kernel(const int* __restrict__ inputs,
                             const float* __restrict__ emb,
                             u16* __restrict__ xbf) {
  int i = blockIdx.x * 256 + threadIdx.x;   // 131072 threads
  int row = i >> 6;
  int e0 = (i & 63) << 3;
  int tok = inputs[row];
  const float* src = emb + (size_t)tok * 512 + e0;
  s16x8 o;
#pragma unroll
  for (int j = 0; j < 8; ++j) o[j] = (short)f2bf(src[j]);
  *(s16x8*)(xbf + (size_t)row * 512 + e0) = o;
}

// bit-pack mask: maskb[b*2+h] bit j = (inputs[b*128 + h*64 + j] != 0)
__global__ void mask_kernel(const int* __restrict__ inputs, u64* __restrict__ mb) {
  int t = threadIdx.x;
  if (t < 32) {
    int b = t >> 1, h = t & 1;
    u64 m = 0;
    for (int j = 0; j < 64; ++j)
      m |= (u64)(inputs[b * 128 + h * 64 + j] != 0) << j;
    mb[t] = m;
  }
}

// Wt[n][k] = bf16(W[k][n]); K,N multiples of 32
__global__ void transpose_bf16(const float* __restrict__ W, u16* __restrict__ Wt,
                               int K, int N) {
  __shared__ float t[32][33];
  int ntn = N >> 5;
  int tn = blockIdx.x % ntn, tk = blockIdx.x / ntn;
  int n0 = tn << 5, k0 = tk << 5;
  int tx = threadIdx.x & 31, ty = threadIdx.x >> 5;  // ty 0..7
#pragma unroll
  for (int j = 0; j < 4; ++j) {
    int k = ty * 4 + j;
    t[k][tx] = W[(size_t)(k0 + k) * N + n0 + tx];
  }
  __syncthreads();
#pragma unroll
  for (int j = 0; j < 4; ++j) {
    int n = ty * 4 + j;
    Wt[(size_t)(n0 + n) * K + k0 + tx] = f2bf(t[tx][n]);
  }
}

// ---------- m97-style bf16 GEMM, 128x128 tile, BK=32 ----------
// MODE 0: C=f32, store acc+bias          (xg)
// MODE 1: C=bf16, store relu(acc+bias)   (d1)
// MODE 2: C=f32, store exp(acc+bias), atomicAdd row sums (logits->exp)
template <int MODE>
__global__ __launch_bounds__(256)
void gemm_bf16(const u16* __restrict__ A, const u16* __restrict__ Bt,
               const float* __restrict__ bias, void* __restrict__ Cptr,
               float* __restrict__ rowsum, int M, int N, int K) {
  (void)M;
  __shared__ u16 sA[128 * 32];
  __shared__ u16 sB[128 * 32];
  const int nbn = N >> 7;
  const int nwg = gridDim.x;
  int bid = blockIdx.x;
  int q = nwg >> 3;                         // grids are multiples of 8
  int swz = (bid & 7) * q + (bid >> 3);     // XCD-aware swizzle (bijective)
  int bm = swz / nbn, bn = swz % nbn;
  const int brow = bm << 7, bcol = bn << 7;

  const int tid = threadIdx.x;
  const int lane = tid & 63;
  const int wv = tid >> 6;
  const int wr = (wv >> 1) * 64, wc = (wv & 1) * 64;
  const int ln = lane & 15, kh = lane >> 4;

  const int srow = tid >> 2;                // 0..63
  const int kch = (tid & 3) << 3;           // 0,8,16,24 (elements)

  f32x4 acc[4][4] = {};

  const int nk = K >> 5;
  const u16* Abase = A + (size_t)(brow + srow) * K + kch;
  const u16* Bbase = Bt + (size_t)(bcol + srow) * K + kch;
  const size_t rstride = (size_t)64 * K;
  u16* lA = sA + srow * 32 + kch;
  u16* lB = sB + srow * 32 + kch;

  for (int kt = 0; kt < nk; ++kt) {
    const int k0 = kt << 5;
    gload_lds16(Abase + k0, lA);
    gload_lds16(Abase + rstride + k0, lA + 64 * 32);
    gload_lds16(Bbase + k0, lB);
    gload_lds16(Bbase + rstride + k0, lB + 64 * 32);
    __syncthreads();
    s16x8 aF[4], bF[4];
#pragma unroll
    for (int m = 0; m < 4; ++m)
      aF[m] = *(const s16x8*)(sA + (wr + m * 16 + ln) * 32 + kh * 8);
#pragma unroll
    for (int n = 0; n < 4; ++n)
      bF[n] = *(const s16x8*)(sB + (wc + n * 16 + ln) * 32 + kh * 8);
#pragma unroll
    for (int m = 0; m < 4; ++m)
#pragma unroll
      for (int n = 0; n < 4; ++n)
        acc[m][n] = __builtin_amdgcn_mfma_f32_16x16x32_bf16(aF[m], bF[n], acc[m][n], 0, 0, 0);
    __syncthreads();
  }

  const int browq = brow + wr;
  const int bcolq = bcol + wc;

  if (MODE == 1) {
    u16* O = (u16*)Cptr;
#pragma unroll
    for (int n = 0; n < 4; ++n) {
      int gcol = bcolq + n * 16 + ln;
      float bv = bias[gcol];
#pragma unroll
      for (int m = 0; m < 4; ++m)
#pragma unroll
        for (int r = 0; r < 4; ++r) {
          int grow = browq + m * 16 + kh * 4 + r;
          float v = fmaxf(acc[m][n][r] + bv, 0.f);
          O[(size_t)grow * N + gcol] = f2bf(v);
        }
    }
  } else {
    float* O = (float*)Cptr;
    float rs[4][4] = {};
#pragma unroll
    for (int n = 0; n < 4; ++n) {
      int gcol = bcolq + n * 16 + ln;
      float bv = bias[gcol];
#pragma unroll
      for (int m = 0; m < 4; ++m)
#pragma unroll
        for (int r = 0; r < 4; ++r) {
          int grow = browq + m * 16 + kh * 4 + r;
          float v = acc[m][n][r] + bv;
          if (MODE == 2) { v = __expf(v); rs[m][r] += v; }
          O[(size_t)grow * N + gcol] = v;
        }
    }
    if (MODE == 2) {
#pragma unroll
      for (int m = 0; m < 4; ++m)
#pragma unroll
        for (int r = 0; r < 4; ++r) {
          float v = rs[m][r];
          v += __shfl_xor(v, 1);
          v += __shfl_xor(v, 2);
          v += __shfl_xor(v, 4);
          v += __shfl_xor(v, 8);
          if (ln == 0) atomicAdd(&rowsum[browq + m * 16 + kh * 4 + r], v);
        }
    }
  }
}

// ---------- persistent LSTM: 32 WGs x 512 threads, full-K waves ----------
// Each WG owns 32 units; wave wv owns units u0+wv*4..+4 x 4 gates (16 cols)
// over the FULL K=1024 (bW[32] = 128 pinned VGPRs). No k-half combine, no
// zxP. Sync = flat relaxed RMW counter, 32 agents (halved contention vs r7).
// Stage/gates/publish identical to r7 (proven numerics).
__global__ __launch_bounds__(512, 1)
void lstm_kernel(const float* __restrict__ xg,      // [2048][4096] f32
                 const u16* __restrict__ Wht,       // [4096][1024] bf16 (n-major)
                 const u64* __restrict__ maskb,     // [16][2] bitmask
                 const float* __restrict__ ench, const float* __restrict__ encc,
                 const float* __restrict__ gamma, const float* __restrict__ beta,
                 const float* __restrict__ mmean, const float* __restrict__ mvar,
                 u32* __restrict__ hbuf32,          // [2][16][512] u32 (linear)
                 u16* __restrict__ hbn,             // [2048][1024] bf16 out
                 u32* __restrict__ cnt) {
  __shared__ char hA[32 * 1024];       // staged h(s), swzB-swizzled

  const int wg = blockIdx.x;           // 0..31
  const int u0 = wg << 5;              // 32 units per WG
  const int tid = threadIdx.x;
  const int lane = tid & 63;
  const int wv = tid >> 6;             // 0..7
  const int ln = lane & 15, khq = lane >> 4;

  const int g = ln & 3;                // gate index (i,f,cc,o)
  const int unit = u0 + wv * 4 + (ln >> 2);

  // ---- Wh preload: full K -> 32 x s16x8 = 128 VGPRs, pinned live ----
  s16x8 bW[32];
  {
    const u16* wrow = Wht + (size_t)(g * 1024 + unit) * 1024 + khq * 8;
#pragma unroll
    for (int kt = 0; kt < 32; ++kt)
      bW[kt] = *(const s16x8*)(wrow + kt * 32);
#pragma unroll
    for (int kt = 0; kt < 32; ++kt)
      asm volatile("" : "+v"(bW[kt]));
  }

  // per-lane state (g==0 lanes meaningful after shfl combine)
  float cellR[4], holdR[4], xgr[4];
  u64 mA[4], mB[4];
  const float bn_s = gamma[unit] * rsqrtf(mvar[unit] + 1e-3f);
  const float bn_b = beta[unit] - mmean[unit] * bn_s;
  const size_t bstride = (size_t)128 * 4096;
  const float* xbase = xg + (size_t)(khq * 4) * bstride + g * 1024 + unit;
#pragma unroll
  for (int r = 0; r < 4; ++r) {
    int batch = khq * 4 + r;
    cellR[r] = encc[batch * 1024 + unit];
    holdR[r] = ench[batch * 1024 + unit];
    mA[r] = maskb[batch * 2];
    mB[r] = maskb[batch * 2 + 1];
  }
  // initial publish of h(0) into parity-0 buffer
#pragma unroll
  for (int r = 0; r < 4; ++r) {
    u32 w = (u32)f2bf(holdR[r]);
    u32 pw = (u32)__shfl_xor((int)w, 4);   // partner unit+1, same gate
    if ((ln & 7) == 0) {
      int batch = khq * 4 + r;
      AT_ST((u32*)((char*)hbuf32 + batch * 2048 + unit * 2), (w & 0xFFFFu) | (pw << 16));
    }
  }
#pragma unroll
  for (int r = 0; r < 4; ++r) xgr[r] = xbase[r * bstride];   // xg(0) prefetch
  asm volatile("s_waitcnt vmcnt(0)" ::: "memory");
  __syncthreads();
  if (tid == 0) {
    u32 oldv = AT_FAA(cnt);
    if (oldv != 31u) {
      int c = 0;
      while (AT_LD((const u32*)cnt) < 32u) {
        __builtin_amdgcn_s_sleep(1);
        if (++c > (1 << 18)) break;
      }
    }
  }
  __syncthreads();

  for (int s = 0; s < 128; ++s) {
    // ---- stage h(s): 8 back-to-back uncached u64 loads, one waitcnt ----
    u64 st[8];
    {
      const u64* base = (const u64*)((const char*)hbuf32 + (s & 1) * 32768) + tid;
#pragma unroll
      for (int k = 0; k < 8; ++k) {
        const u64* pp = base + k * 512;
        asm volatile("global_load_dwordx2 %0, %1, off sc0 sc1" : "=v"(st[k]) : "v"(pp));
      }
      asm volatile("s_waitcnt vmcnt(0)" ::: "memory");
      __builtin_amdgcn_sched_barrier(0);
#pragma unroll
      for (int k = 0; k < 8; ++k)
        *(u64*)(hA + swzB((tid + k * 512) * 8)) = st[k];
    }
    __syncthreads();                           // (A) hA ready

    // ---- 32 MFMA over full K, 2 chains; A from LDS, B pinned in VGPRs ----
    f32x4 acc0 = {0.f, 0.f, 0.f, 0.f};
    f32x4 acc1 = {0.f, 0.f, 0.f, 0.f};
#pragma unroll
    for (int kt = 0; kt < 32; kt += 2) {
      s16x8 a0 = *(const s16x8*)(hA + swzB(ln * 2048 + kt * 64 + khq * 16));
      acc0 = __builtin_amdgcn_mfma_f32_16x16x32_bf16(a0, bW[kt], acc0, 0, 0, 0);
      s16x8 a1 = *(const s16x8*)(hA + swzB(ln * 2048 + (kt + 1) * 64 + khq * 16));
      acc1 = __builtin_amdgcn_mfma_f32_16x16x32_bf16(a1, bW[kt + 1], acc1, 0, 0, 0);
    }
    f32x4 accs = acc0 + acc1;

    // ---- gates fully in-wave (lane quads hold i,f,cc,o) + publish ----
    u32 bnpair[4];
    {
      u16 hbb[4], hbnb[4];
#pragma unroll
      for (int r = 0; r < 4; ++r) {
        float z = accs[r] + xgr[r];
        float sig = 1.f / (1.f + __expf(-z));
        float val = (g == 2) ? fmaxf(z, 0.f) : sig;
        float v1 = __shfl_xor(val, 1);
        float v2 = __shfl_xor(val, 2);
        float v3 = __shfl_xor(val, 3);
        float cnew = v1 * cellR[r] + val * v2;   // f*c + i*cc (g==0 view)
        float hnew = v3 * fmaxf(cnew, 0.f);
        u64 mm = (s < 64) ? mA[r] : mB[r];
        if (!((mm >> (s & 63)) & 1)) { cnew = cellR[r]; hnew = holdR[r]; }
        cellR[r] = cnew;
        holdR[r] = hnew;
        hbb[r] = f2bf(hnew);
        hbnb[r] = f2bf(hnew * bn_s + bn_b);
      }
#pragma unroll
      for (int r = 0; r < 4; ++r) {
        u32 w = (u32)hbb[r] | ((u32)hbnb[r] << 16);
        u32 pw = (u32)__shfl_xor((int)w, 4);
        u32 hpair = (w & 0xFFFFu) | ((pw & 0xFFFFu) << 16);
        bnpair[r] = (w >> 16) | (pw & 0xFFFF0000u);
        if (s < 127 && (ln & 7) == 0) {
          int batch = khq * 4 + r;
          AT_ST((u32*)((char*)hbuf32 + ((s + 1) & 1) * 32768 + batch * 2048 + unit * 2), hpair);
        }
      }
    }

    if (s < 127) {
      asm volatile("s_waitcnt vmcnt(0)" ::: "memory");   // drain h publishes
      __syncthreads();                         // (B) all publishes complete
      u32 oldv = 0xFFFFFFFFu;
      if (tid == 0) oldv = AT_FAA(cnt);
      // deferred hbn stores + xg(s+1) prefetch overlap the poll
      if ((ln & 7) == 0) {
#pragma unroll
        for (int r = 0; r < 4; ++r) {
          int batch = khq * 4 + r;
          *(u32*)((char*)hbn + (size_t)(batch * 128 + s) * 2048 + unit * 2) = bnpair[r];
        }
      }
      {
        const float* xb = xbase + (size_t)(s + 1) * 4096;
#pragma unroll
        for (int r = 0; r < 4; ++r) xgr[r] = xb[r * bstride];
      }
      if (tid == 0) {
        const u32 target = (u32)(s + 2) * 32u;
        if (oldv != target - 1u) {
          int c = 0;
          while (AT_LD((const u32*)cnt) < target) {
            __builtin_amdgcn_s_sleep(1);
            if (++c > (1 << 18)) break;
          }
        }
      }
      __syncthreads();                         // (C) release
    } else if ((ln & 7) == 0) {
      // s == 127: final hbn stores
#pragma unroll
      for (int r = 0; r < 4; ++r) {
        int batch = khq * 4 + r;
        *(u32*)((char*)hbn + (size_t)(batch * 128 + s) * 2048 + unit * 2) = bnpair[r];
      }
    }
  }
}

// ---------- softmax finish (rcp fused) ----------

__global__ void scale_kernel(float* __restrict__ out, const float* __restrict__ rs) {
  const int total4 = 16384000;              // 65,536,000 / 4
  for (int i = blockIdx.x * 256 + threadIdx.x; i < total4; i += gridDim.x * 256) {
    float4* p = (float4*)out + i;
    float4 v = *p;
    int row = i / 8000;                     // 8000 float4 per row
    float sF = 1.0f / rs[row];
    v.x *= sF; v.y *= sF; v.z *= sF; v.w *= sF;
    *p = v;
  }
}

// ---------- launch ----------

extern "C" void kernel_launch(void* const* d_in, const int* in_sizes, int n_in,
                              void* d_out, int out_size, void* d_ws, size_t ws_size,
                              hipStream_t stream) {
  (void)in_sizes; (void)n_in; (void)out_size;
  const int*   inputs = (const int*)d_in[0];
  const float* ench   = (const float*)d_in[1];
  const float* encc   = (const float*)d_in[2];
  const float* emb    = (const float*)d_in[3];
  const float* Wx     = (const float*)d_in[4];
  const float* Wh     = (const float*)d_in[5];
  const float* bb     = (const float*)d_in[6];
  const float* gamma  = (const float*)d_in[7];
  const float* beta   = (const float*)d_in[8];
  const float* mmean  = (const float*)d_in[9];
  const float* mvar   = (const float*)d_in[10];
  const float* W1     = (const float*)d_in[11];
  const float* b1     = (const float*)d_in[12];
  const float* W2     = (const float*)d_in[13];
  const float* b2     = (const float*)d_in[14];
  float* out = (float*)d_out;

  char* p = (char*)d_ws;
  u32*   cnt    = (u32*)(p + 0);            // word 0
  float* rowsum = (float*)(p + 1024);       // 2048 floats; memset covers [0,9216)
  u64*   maskb  = (u64*)(p + 10240);        // 256B, written by mask_kernel
  u32*   hbuf32 = (u32*)(p + 16384);        // 64KB (2 x 32KB parity tiles)
  size_t off = 81920;
  u16*   xbf  = (u16*)(p + off);     off += (size_t)2048 * 512 * 2;     // 2MB
  u16*   Wxt  = (u16*)(p + off);     off += (size_t)4096 * 512 * 2;     // 4MB
  u16*   Wht  = (u16*)(p + off);     off += (size_t)4096 * 1024 * 2;    // 8MB
  u16*   W1t  = (u16*)(p + off);     off += (size_t)1024 * 1024 * 2;    // 2MB
  u16*   W2t  = (u16*)(p + off);     off += (size_t)32000 * 1024 * 2;   // 64MB
  float* xg   = (float*)(p + off);   off += (size_t)2048 * 4096 * 4;    // 32MB
  u16*   hbn  = (u16*)(p + off);     off += (size_t)2048 * 1024 * 2;    // 4MB
  u16*   d1   = (u16*)(p + off);     off += (size_t)2048 * 1024 * 2;    // 4MB
  if (ws_size < off) return;  // insufficient scratch; avoid OOB

  hipMemsetAsync(d_ws, 0, 9216, stream);  // cnt + rowsum

  embed_kernel<<<512, 256, 0, stream>>>(inputs, emb, xbf);
  mask_kernel<<<1, 64, 0, stream>>>(inputs, maskb);
  transpose_bf16<<<(512 / 32) * (4096 / 32), 256, 0, stream>>>(Wx, Wxt, 512, 4096);
  transpose_bf16<<<(1024 / 32) * (4096 / 32), 256, 0, stream>>>(Wh, Wht, 1024, 4096);
  transpose_bf16<<<(1024 / 32) * (1024 / 32), 256, 0, stream>>>(W1, W1t, 1024, 1024);
  transpose_bf16<<<(1024 / 32) * (32000 / 32), 256, 0, stream>>>(W2, W2t, 1024, 32000);

  gemm_bf16<0><<<16 * 32, 256, 0, stream>>>(xbf, Wxt, bb, xg, nullptr, 2048, 4096, 512);

  lstm_kernel<<<32, 512, 0, stream>>>(xg, Wht, maskb, ench, encc, gamma, beta,
                                      mmean, mvar, hbuf32, hbn, cnt);

  gemm_bf16<1><<<16 * 8, 256, 0, stream>>>(hbn, W1t, b1, d1, nullptr, 2048, 1024, 1024);
  gemm_bf16<2><<<16 * 250, 256, 0, stream>>>(d1, W2t, b2, out, rowsum, 2048, 32000, 1024);

  scale_kernel<<<2048, 256, 0, stream>>>(out, rowsum);
}

// Round 11
// 962.155 us; speedup vs baseline: 2.1498x; 1.0170x over previous
//
#include <hip/hip_runtime.h>
#include <hip/hip_bf16.h>
#include <stdint.h>

typedef unsigned short u16;
typedef unsigned int u32;
typedef unsigned long long u64;
typedef __attribute__((ext_vector_type(4))) float f32x4;
typedef __attribute__((ext_vector_type(8))) short s16x8;
typedef __attribute__((ext_vector_type(4))) unsigned int u32x4;

#define AT_LD(p)    __hip_atomic_load((p), __ATOMIC_RELAXED, __HIP_MEMORY_SCOPE_AGENT)
#define AT_ST(p, v) __hip_atomic_store((p), (v), __ATOMIC_RELAXED, __HIP_MEMORY_SCOPE_AGENT)
#define AT_FAA(p)   __hip_atomic_fetch_add((p), 1u, __ATOMIC_RELAXED, __HIP_MEMORY_SCOPE_AGENT)

// ---------- helpers ----------

static __device__ __forceinline__ u16 f2bf(float f) {
  union { float f; unsigned u; } v; v.f = f;
  unsigned r = v.u + 0x7FFFu + ((v.u >> 16) & 1u);
  return (u16)(r >> 16);
}

static __device__ __forceinline__ float bf2f(u16 b) {
  union { unsigned u; float f; } v; v.u = ((u32)b) << 16;
  return v.f;
}

static __device__ __forceinline__ void gload_lds16(const void* g, void* l) {
  __builtin_amdgcn_global_load_lds(
      (const __attribute__((address_space(1))) unsigned int*)(uintptr_t)g,
      (__attribute__((address_space(3))) unsigned int*)(uintptr_t)l,
      16, 0, 0);
}

// bank-balancing swizzle for the 32KB h tile in LDS (r6/r7 proven).
static __device__ __forceinline__ int swzB(int B) {
  int pos = (B >> 4) & 127;
  int row = (B >> 11) & 15;
  int slot = (pos ^ row ^ (pos >> 3)) & 7;
  int npos = (pos & 0x78) | slot;
  return (B & ~0x7F0) | (npos << 4);
}

// ---------- pre-pass kernels ----------

__global__ void embed_kernel(const int* __restrict__ inputs,
                             const float* __restrict__ emb,
                             u16* __restrict__ xbf) {
  int i = blockIdx.x * 256 + threadIdx.x;   // 131072 threads
  int row = i >> 6;
  int e0 = (i & 63) << 3;
  int tok = inputs[row];
  const float* src = emb + (size_t)tok * 512 + e0;
  s16x8 o;
#pragma unroll
  for (int j = 0; j < 8; ++j) o[j] = (short)f2bf(src[j]);
  *(s16x8*)(xbf + (size_t)row * 512 + e0) = o;
}

// bit-pack mask: maskb[b*2+h] bit j = (inputs[b*128 + h*64 + j] != 0)
__global__ void mask_kernel(const int* __restrict__ inputs, u64* __restrict__ mb) {
  int t = threadIdx.x;
  if (t < 32) {
    int b = t >> 1, h = t & 1;
    u64 m = 0;
    for (int j = 0; j < 64; ++j)
      m |= (u64)(inputs[b * 128 + h * 64 + j] != 0) << j;
    mb[t] = m;
  }
}

// Wt[n][k] = bf16(W[k][n]); K,N multiples of 32
__global__ void transpose_bf16(const float* __restrict__ W, u16* __restrict__ Wt,
                               int K, int N) {
  __shared__ float t[32][33];
  int ntn = N >> 5;
  int tn = blockIdx.x % ntn, tk = blockIdx.x / ntn;
  int n0 = tn << 5, k0 = tk << 5;
  int tx = threadIdx.x & 31, ty = threadIdx.x >> 5;  // ty 0..7
#pragma unroll
  for (int j = 0; j < 4; ++j) {
    int k = ty * 4 + j;
    t[k][tx] = W[(size_t)(k0 + k) * N + n0 + tx];
  }
  __syncthreads();
#pragma unroll
  for (int j = 0; j < 4; ++j) {
    int n = ty * 4 + j;
    Wt[(size_t)(n0 + n) * K + k0 + tx] = f2bf(t[tx][n]);
  }
}

// ---------- m97-style bf16 GEMM, 128x128 tile, BK=32 ----------
// MODE 0: C=f32, store acc+bias          (xg)
// MODE 1: C=bf16, store relu(acc+bias)   (d1)
// MODE 2: C=f32, store exp(acc+bias), atomicAdd row sums (logits->exp)
// MODE 3: C=bf16, store exp(acc+bias), atomicAdd row sums
template <int MODE>
__global__ __launch_bounds__(256)
void gemm_bf16(const u16* __restrict__ A, const u16* __restrict__ Bt,
               const float* __restrict__ bias, void* __restrict__ Cptr,
               float* __restrict__ rowsum, int M, int N, int K) {
  (void)M;
  __shared__ u16 sA[128 * 32];
  __shared__ u16 sB[128 * 32];
  const int nbn = N >> 7;
  const int nwg = gridDim.x;
  int bid = blockIdx.x;
  int q = nwg >> 3;                         // grids are multiples of 8
  int swz = (bid & 7) * q + (bid >> 3);     // XCD-aware swizzle (bijective)
  int bm = swz / nbn, bn = swz % nbn;
  const int brow = bm << 7, bcol = bn << 7;

  const int tid = threadIdx.x;
  const int lane = tid & 63;
  const int wv = tid >> 6;
  const int wr = (wv >> 1) * 64, wc = (wv & 1) * 64;
  const int ln = lane & 15, kh = lane >> 4;

  const int srow = tid >> 2;                // 0..63
  const int kch = (tid & 3) << 3;           // 0,8,16,24 (elements)

  f32x4 acc[4][4] = {};

  const int nk = K >> 5;
  const u16* Abase = A + (size_t)(brow + srow) * K + kch;
  const u16* Bbase = Bt + (size_t)(bcol + srow) * K + kch;
  const size_t rstride = (size_t)64 * K;
  u16* lA = sA + srow * 32 + kch;
  u16* lB = sB + srow * 32 + kch;

  for (int kt = 0; kt < nk; ++kt) {
    const int k0 = kt << 5;
    gload_lds16(Abase + k0, lA);
    gload_lds16(Abase + rstride + k0, lA + 64 * 32);
    gload_lds16(Bbase + k0, lB);
    gload_lds16(Bbase + rstride + k0, lB + 64 * 32);
    __syncthreads();
    s16x8 aF[4], bF[4];
#pragma unroll
    for (int m = 0; m < 4; ++m)
      aF[m] = *(const s16x8*)(sA + (wr + m * 16 + ln) * 32 + kh * 8);
#pragma unroll
    for (int n = 0; n < 4; ++n)
      bF[n] = *(const s16x8*)(sB + (wc + n * 16 + ln) * 32 + kh * 8);
#pragma unroll
    for (int m = 0; m < 4; ++m)
#pragma unroll
      for (int n = 0; n < 4; ++n)
        acc[m][n] = __builtin_amdgcn_mfma_f32_16x16x32_bf16(aF[m], bF[n], acc[m][n], 0, 0, 0);
    __syncthreads();
  }

  const int browq = brow + wr;
  const int bcolq = bcol + wc;

  if (MODE == 1) {
    u16* O = (u16*)Cptr;
#pragma unroll
    for (int n = 0; n < 4; ++n) {
      int gcol = bcolq + n * 16 + ln;
      float bv = bias[gcol];
#pragma unroll
      for (int m = 0; m < 4; ++m)
#pragma unroll
        for (int r = 0; r < 4; ++r) {
          int grow = browq + m * 16 + kh * 4 + r;
          float v = fmaxf(acc[m][n][r] + bv, 0.f);
          O[(size_t)grow * N + gcol] = f2bf(v);
        }
    }
  } else if (MODE == 3) {
    u16* O = (u16*)Cptr;
    float rs[4][4] = {};
#pragma unroll
    for (int n = 0; n < 4; ++n) {
      int gcol = bcolq + n * 16 + ln;
      float bv = bias[gcol];
#pragma unroll
      for (int m = 0; m < 4; ++m)
#pragma unroll
        for (int r = 0; r < 4; ++r) {
          int grow = browq + m * 16 + kh * 4 + r;
          float v = __expf(acc[m][n][r] + bv);
          rs[m][r] += v;
          O[(size_t)grow * N + gcol] = f2bf(v);
        }
    }
#pragma unroll
    for (int m = 0; m < 4; ++m)
#pragma unroll
      for (int r = 0; r < 4; ++r) {
        float v = rs[m][r];
        v += __shfl_xor(v, 1);
        v += __shfl_xor(v, 2);
        v += __shfl_xor(v, 4);
        v += __shfl_xor(v, 8);
        if (ln == 0) atomicAdd(&rowsum[browq + m * 16 + kh * 4 + r], v);
      }
  } else {
    float* O = (float*)Cptr;
    float rs[4][4] = {};
#pragma unroll
    for (int n = 0; n < 4; ++n) {
      int gcol = bcolq + n * 16 + ln;
      float bv = bias[gcol];
#pragma unroll
      for (int m = 0; m < 4; ++m)
#pragma unroll
        for (int r = 0; r < 4; ++r) {
          int grow = browq + m * 16 + kh * 4 + r;
          float v = acc[m][n][r] + bv;
          if (MODE == 2) { v = __expf(v); rs[m][r] += v; }
          O[(size_t)grow * N + gcol] = v;
        }
    }
    if (MODE == 2) {
#pragma unroll
      for (int m = 0; m < 4; ++m)
#pragma unroll
        for (int r = 0; r < 4; ++r) {
          float v = rs[m][r];
          v += __shfl_xor(v, 1);
          v += __shfl_xor(v, 2);
          v += __shfl_xor(v, 4);
          v += __shfl_xor(v, 8);
          if (ln == 0) atomicAdd(&rowsum[browq + m * 16 + kh * 4 + r], v);
        }
    }
  }
}

// ---------- persistent LSTM: 32 WGs x 512 threads, full-K waves ----------
// r10 structure; Wh loaded via inline-asm global_load_dwordx4 so the 128
// result VGPRs CANNOT be rematerialized (r10's VGPR_Count=116 proved the
// compiler was re-loading Wh from L2 inside every step's MFMA loop).
__global__ __launch_bounds__(512, 1)
void lstm_kernel(const float* __restrict__ xg,      // [2048][4096] f32
                 const u16* __restrict__ Wht,       // [4096][1024] bf16 (n-major)
                 const u64* __restrict__ maskb,     // [16][2] bitmask
                 const float* __restrict__ ench, const float* __restrict__ encc,
                 const float* __restrict__ gamma, const float* __restrict__ beta,
                 const float* __restrict__ mmean, const float* __restrict__ mvar,
                 u32* __restrict__ hbuf32,          // [2][16][512] u32 (linear)
                 u16* __restrict__ hbn,             // [2048][1024] bf16 out
                 u32* __restrict__ cnt) {
  __shared__ char hA[32 * 1024];       // staged h(s), swzB-swizzled

  const int wg = blockIdx.x;           // 0..31
  const int u0 = wg << 5;              // 32 units per WG
  const int tid = threadIdx.x;
  const int lane = tid & 63;
  const int wv = tid >> 6;             // 0..7
  const int ln = lane & 15, khq = lane >> 4;

  const int g = ln & 3;                // gate index (i,f,cc,o)
  const int unit = u0 + wv * 4 + (ln >> 2);

  // ---- Wh preload: 32 x 16B via inline asm -> un-rematerializable ----
  u32x4 bWq[32];
  {
    const u16* wrow = Wht + (size_t)(g * 1024 + unit) * 1024 + khq * 8;
#pragma unroll
    for (int kt = 0; kt < 32; ++kt) {
      const u16* pp = wrow + kt * 32;
      asm volatile("global_load_dwordx4 %0, %1, off" : "=v"(bWq[kt]) : "v"(pp));
    }
    asm volatile("s_waitcnt vmcnt(0)" ::: "memory");
  }

  // per-lane state (g==0 lanes meaningful after shfl combine)
  float cellR[4], holdR[4], xgr[4];
  u64 mA[4], mB[4];
  const float bn_s = gamma[unit] * rsqrtf(mvar[unit] + 1e-3f);
  const float bn_b = beta[unit] - mmean[unit] * bn_s;
  const size_t bstride = (size_t)128 * 4096;
  const float* xbase = xg + (size_t)(khq * 4) * bstride + g * 1024 + unit;
#pragma unroll
  for (int r = 0; r < 4; ++r) {
    int batch = khq * 4 + r;
    cellR[r] = encc[batch * 1024 + unit];
    holdR[r] = ench[batch * 1024 + unit];
    mA[r] = maskb[batch * 2];
    mB[r] = maskb[batch * 2 + 1];
  }
  // initial publish of h(0) into parity-0 buffer
#pragma unroll
  for (int r = 0; r < 4; ++r) {
    u32 w = (u32)f2bf(holdR[r]);
    u32 pw = (u32)__shfl_xor((int)w, 4);   // partner unit+1, same gate
    if ((ln & 7) == 0) {
      int batch = khq * 4 + r;
      AT_ST((u32*)((char*)hbuf32 + batch * 2048 + unit * 2), (w & 0xFFFFu) | (pw << 16));
    }
  }
#pragma unroll
  for (int r = 0; r < 4; ++r) xgr[r] = xbase[r * bstride];   // xg(0) prefetch
  asm volatile("s_waitcnt vmcnt(0)" ::: "memory");
  __syncthreads();
  if (tid == 0) {
    u32 oldv = AT_FAA(cnt);
    if (oldv != 31u) {
      int c = 0;
      while (AT_LD((const u32*)cnt) < 32u) {
        __builtin_amdgcn_s_sleep(1);
        if (++c > (1 << 18)) break;
      }
    }
  }
  __syncthreads();

  for (int s = 0; s < 128; ++s) {
    // ---- stage h(s): 8 back-to-back uncached u64 loads, one waitcnt ----
    u64 st[8];
    {
      const u64* base = (const u64*)((const char*)hbuf32 + (s & 1) * 32768) + tid;
#pragma unroll
      for (int k = 0; k < 8; ++k) {
        const u64* pp = base + k * 512;
        asm volatile("global_load_dwordx2 %0, %1, off sc0 sc1" : "=v"(st[k]) : "v"(pp));
      }
      asm volatile("s_waitcnt vmcnt(0)" ::: "memory");
      __builtin_amdgcn_sched_barrier(0);
#pragma unroll
      for (int k = 0; k < 8; ++k)
        *(u64*)(hA + swzB((tid + k * 512) * 8)) = st[k];
    }
    __syncthreads();                           // (A) hA ready

    // ---- 32 MFMA over full K, 2 chains; A from LDS, B resident in VGPRs ----
    f32x4 acc0 = {0.f, 0.f, 0.f, 0.f};
    f32x4 acc1 = {0.f, 0.f, 0.f, 0.f};
#pragma unroll
    for (int kt = 0; kt < 32; kt += 2) {
      s16x8 a0 = *(const s16x8*)(hA + swzB(ln * 2048 + kt * 64 + khq * 16));
      acc0 = __builtin_amdgcn_mfma_f32_16x16x32_bf16(
          a0, __builtin_bit_cast(s16x8, bWq[kt]), acc0, 0, 0, 0);
      s16x8 a1 = *(const s16x8*)(hA + swzB(ln * 2048 + (kt + 1) * 64 + khq * 16));
      acc1 = __builtin_amdgcn_mfma_f32_16x16x32_bf16(
          a1, __builtin_bit_cast(s16x8, bWq[kt + 1]), acc1, 0, 0, 0);
    }
    f32x4 accs = acc0 + acc1;

    // ---- gates fully in-wave (lane quads hold i,f,cc,o) + publish ----
    u32 bnpair[4];
    {
      u16 hbb[4], hbnb[4];
#pragma unroll
      for (int r = 0; r < 4; ++r) {
        float z = accs[r] + xgr[r];
        float sig = 1.f / (1.f + __expf(-z));
        float val = (g == 2) ? fmaxf(z, 0.f) : sig;
        float v1 = __shfl_xor(val, 1);
        float v2 = __shfl_xor(val, 2);
        float v3 = __shfl_xor(val, 3);
        float cnew = v1 * cellR[r] + val * v2;   // f*c + i*cc (g==0 view)
        float hnew = v3 * fmaxf(cnew, 0.f);
        u64 mm = (s < 64) ? mA[r] : mB[r];
        if (!((mm >> (s & 63)) & 1)) { cnew = cellR[r]; hnew = holdR[r]; }
        cellR[r] = cnew;
        holdR[r] = hnew;
        hbb[r] = f2bf(hnew);
        hbnb[r] = f2bf(hnew * bn_s + bn_b);
      }
#pragma unroll
      for (int r = 0; r < 4; ++r) {
        u32 w = (u32)hbb[r] | ((u32)hbnb[r] << 16);
        u32 pw = (u32)__shfl_xor((int)w, 4);
        u32 hpair = (w & 0xFFFFu) | ((pw & 0xFFFFu) << 16);
        bnpair[r] = (w >> 16) | (pw & 0xFFFF0000u);
        if (s < 127 && (ln & 7) == 0) {
          int batch = khq * 4 + r;
          AT_ST((u32*)((char*)hbuf32 + ((s + 1) & 1) * 32768 + batch * 2048 + unit * 2), hpair);
        }
      }
    }

    if (s < 127) {
      asm volatile("s_waitcnt vmcnt(0)" ::: "memory");   // drain h publishes
      __syncthreads();                         // (B) all publishes complete
      u32 oldv = 0xFFFFFFFFu;
      if (tid == 0) oldv = AT_FAA(cnt);
      // deferred hbn stores + xg(s+1) prefetch overlap the poll
      if ((ln & 7) == 0) {
#pragma unroll
        for (int r = 0; r < 4; ++r) {
          int batch = khq * 4 + r;
          *(u32*)((char*)hbn + (size_t)(batch * 128 + s) * 2048 + unit * 2) = bnpair[r];
        }
      }
      {
        const float* xb = xbase + (size_t)(s + 1) * 4096;
#pragma unroll
        for (int r = 0; r < 4; ++r) xgr[r] = xb[r * bstride];
      }
      if (tid == 0) {
        const u32 target = (u32)(s + 2) * 32u;
        if (oldv != target - 1u) {
          int c = 0;
          while (AT_LD((const u32*)cnt) < target) {
            __builtin_amdgcn_s_sleep(1);
            if (++c > (1 << 18)) break;
          }
        }
      }
      __syncthreads();                         // (C) release
    } else if ((ln & 7) == 0) {
      // s == 127: final hbn stores
#pragma unroll
      for (int r = 0; r < 4; ++r) {
        int batch = khq * 4 + r;
        *(u32*)((char*)hbn + (size_t)(batch * 128 + s) * 2048 + unit * 2) = bnpair[r];
      }
    }
  }
}

// ---------- softmax finish ----------

// f32 path (fallback): in-place scale of f32 exp
__global__ void scale_kernel(float* __restrict__ out, const float* __restrict__ rs) {
  const int total4 = 16384000;              // 65,536,000 / 4
  for (int i = blockIdx.x * 256 + threadIdx.x; i < total4; i += gridDim.x * 256) {
    float4* p = (float4*)out + i;
    float4 v = *p;
    int row = i / 8000;                     // 8000 float4 per row
    float sF = 1.0f / rs[row];
    v.x *= sF; v.y *= sF; v.z *= sF; v.w *= sF;
    *p = v;
  }
}

// bf16 path: read bf16 exp, write normalized f32
__global__ void scale_bf_kernel(float* __restrict__ out, const u16* __restrict__ e,
                                const float* __restrict__ rs) {
  const int total8 = 8192000;               // 65,536,000 / 8
  for (int i = blockIdx.x * 256 + threadIdx.x; i < total8; i += gridDim.x * 256) {
    s16x8 v = ((const s16x8*)e)[i];
    int row = i / 4000;                     // 4000 8-groups per row
    float sF = 1.0f / rs[row];
    float4 o0, o1;
    o0.x = bf2f((u16)v[0]) * sF; o0.y = bf2f((u16)v[1]) * sF;
    o0.z = bf2f((u16)v[2]) * sF; o0.w = bf2f((u16)v[3]) * sF;
    o1.x = bf2f((u16)v[4]) * sF; o1.y = bf2f((u16)v[5]) * sF;
    o1.z = bf2f((u16)v[6]) * sF; o1.w = bf2f((u16)v[7]) * sF;
    ((float4*)out)[2 * i] = o0;
    ((float4*)out)[2 * i + 1] = o1;
  }
}

// ---------- launch ----------

extern "C" void kernel_launch(void* const* d_in, const int* in_sizes, int n_in,
                              void* d_out, int out_size, void* d_ws, size_t ws_size,
                              hipStream_t stream) {
  (void)in_sizes; (void)n_in; (void)out_size;
  const int*   inputs = (const int*)d_in[0];
  const float* ench   = (const float*)d_in[1];
  const float* encc   = (const float*)d_in[2];
  const float* emb    = (const float*)d_in[3];
  const float* Wx     = (const float*)d_in[4];
  const float* Wh     = (const float*)d_in[5];
  const float* bb     = (const float*)d_in[6];
  const float* gamma  = (const float*)d_in[7];
  const float* beta   = (const float*)d_in[8];
  const float* mmean  = (const float*)d_in[9];
  const float* mvar   = (const float*)d_in[10];
  const float* W1     = (const float*)d_in[11];
  const float* b1     = (const float*)d_in[12];
  const float* W2     = (const float*)d_in[13];
  const float* b2     = (const float*)d_in[14];
  float* out = (float*)d_out;

  char* p = (char*)d_ws;
  u32*   cnt    = (u32*)(p + 0);            // word 0
  float* rowsum = (float*)(p + 1024);       // 2048 floats; memset covers [0,9216)
  u64*   maskb  = (u64*)(p + 10240);        // 256B, written by mask_kernel
  u32*   hbuf32 = (u32*)(p + 16384);        // 64KB (2 x 32KB parity tiles)
  size_t off = 81920;
  u16*   xbf  = (u16*)(p + off);     off += (size_t)2048 * 512 * 2;     // 2MB
  u16*   Wxt  = (u16*)(p + off);     off += (size_t)4096 * 512 * 2;     // 4MB
  u16*   Wht  = (u16*)(p + off);     off += (size_t)4096 * 1024 * 2;    // 8MB
  u16*   W1t  = (u16*)(p + off);     off += (size_t)1024 * 1024 * 2;    // 2MB
  u16*   W2t  = (u16*)(p + off);     off += (size_t)32000 * 1024 * 2;   // 64MB
  float* xg   = (float*)(p + off);   off += (size_t)2048 * 4096 * 4;    // 32MB
  u16*   hbn  = (u16*)(p + off);     off += (size_t)2048 * 1024 * 2;    // 4MB
  u16*   d1   = (u16*)(p + off);     off += (size_t)2048 * 1024 * 2;    // 4MB
  size_t off_base = off;
  u16*   expbf = (u16*)(p + off);    off += (size_t)2048 * 32000 * 2;   // 125MB (optional)
  if (ws_size < off_base) return;  // insufficient scratch; avoid OOB
  const bool bf16path = (ws_size >= off);

  hipMemsetAsync(d_ws, 0, 9216, stream);  // cnt + rowsum

  embed_kernel<<<512, 256, 0, stream>>>(inputs, emb, xbf);
  mask_kernel<<<1, 64, 0, stream>>>(inputs, maskb);
  transpose_bf16<<<(512 / 32) * (4096 / 32), 256, 0, stream>>>(Wx, Wxt, 512, 4096);
  transpose_bf16<<<(1024 / 32) * (4096 / 32), 256, 0, stream>>>(Wh, Wht, 1024, 4096);
  transpose_bf16<<<(1024 / 32) * (1024 / 32), 256, 0, stream>>>(W1, W1t, 1024, 1024);
  transpose_bf16<<<(1024 / 32) * (32000 / 32), 256, 0, stream>>>(W2, W2t, 1024, 32000);

  gemm_bf16<0><<<16 * 32, 256, 0, stream>>>(xbf, Wxt, bb, xg, nullptr, 2048, 4096, 512);

  lstm_kernel<<<32, 512, 0, stream>>>(xg, Wht, maskb, ench, encc, gamma, beta,
                                      mmean, mvar, hbuf32, hbn, cnt);

  gemm_bf16<1><<<16 * 8, 256, 0, stream>>>(hbn, W1t, b1, d1, nullptr, 2048, 1024, 1024);

  if (bf16path) {
    gemm_bf16<3><<<16 * 250, 256, 0, stream>>>(d1, W2t, b2, expbf, rowsum, 2048, 32000, 1024);
    scale_bf_kernel<<<2048, 256, 0, stream>>>(out, expbf, rowsum);
  } else {
    gemm_bf16<2><<<16 * 250, 256, 0, stream>>>(d1, W2t, b2, out, rowsum, 2048, 32000, 1024);
    scale_kernel<<<2048, 256, 0, stream>>>(out, rowsum);
  }
}

// Round 12
// 898.252 us; speedup vs baseline: 2.3028x; 1.0711x over previous
//
#include <hip/hip_runtime.h>
#include <hip/hip_bf16.h>
#include <stdint.h>

typedef unsigned short u16;
typedef unsigned int u32;
typedef unsigned long long u64;
typedef __attribute__((ext_vector_type(4))) float f32x4;
typedef __attribute__((ext_vector_type(8))) short s16x8;
typedef __attribute__((ext_vector_type(4))) unsigned int u32x4;

#define AT_LD(p)    __hip_atomic_load((p), __ATOMIC_RELAXED, __HIP_MEMORY_SCOPE_AGENT)
#define AT_ST(p, v) __hip_atomic_store((p), (v), __ATOMIC_RELAXED, __HIP_MEMORY_SCOPE_AGENT)
#define AT_FAA(p)   __hip_atomic_fetch_add((p), 1u, __ATOMIC_RELAXED, __HIP_MEMORY_SCOPE_AGENT)

// ---------- helpers ----------

static __device__ __forceinline__ u16 f2bf(float f) {
  union { float f; unsigned u; } v; v.f = f;
  unsigned r = v.u + 0x7FFFu + ((v.u >> 16) & 1u);
  return (u16)(r >> 16);
}

static __device__ __forceinline__ float bf2f(u16 b) {
  union { unsigned u; float f; } v; v.u = ((u32)b) << 16;
  return v.f;
}

static __device__ __forceinline__ void gload_lds16(const void* g, void* l) {
  __builtin_amdgcn_global_load_lds(
      (const __attribute__((address_space(1))) unsigned int*)(uintptr_t)g,
      (__attribute__((address_space(3))) unsigned int*)(uintptr_t)l,
      16, 0, 0);
}

// bank-balancing swizzle for the 32KB h tile in LDS (r6/r7 proven).
static __device__ __forceinline__ int swzB(int B) {
  int pos = (B >> 4) & 127;
  int row = (B >> 11) & 15;
  int slot = (pos ^ row ^ (pos >> 3)) & 7;
  int npos = (pos & 0x78) | slot;
  return (B & ~0x7F0) | (npos << 4);
}

// ---------- pre-pass kernels ----------

__global__ void embed_kernel(const int* __restrict__ inputs,
                             const float* __restrict__ emb,
                             u16* __restrict__ xbf) {
  int i = blockIdx.x * 256 + threadIdx.x;   // 131072 threads
  int row = i >> 6;
  int e0 = (i & 63) << 3;
  int tok = inputs[row];
  const float* src = emb + (size_t)tok * 512 + e0;
  s16x8 o;
#pragma unroll
  for (int j = 0; j < 8; ++j) o[j] = (short)f2bf(src[j]);
  *(s16x8*)(xbf + (size_t)row * 512 + e0) = o;
}

// bit-pack mask: maskb[b*2+h] bit j = (inputs[b*128 + h*64 + j] != 0)
__global__ void mask_kernel(const int* __restrict__ inputs, u64* __restrict__ mb) {
  int t = threadIdx.x;
  if (t < 32) {
    int b = t >> 1, h = t & 1;
    u64 m = 0;
    for (int j = 0; j < 64; ++j)
      m |= (u64)(inputs[b * 128 + h * 64 + j] != 0) << j;
    mb[t] = m;
  }
}

// Wt[n][k] = bf16(W[k][n]); K,N multiples of 32
__global__ void transpose_bf16(const float* __restrict__ W, u16* __restrict__ Wt,
                               int K, int N) {
  __shared__ float t[32][33];
  int ntn = N >> 5;
  int tn = blockIdx.x % ntn, tk = blockIdx.x / ntn;
  int n0 = tn << 5, k0 = tk << 5;
  int tx = threadIdx.x & 31, ty = threadIdx.x >> 5;  // ty 0..7
#pragma unroll
  for (int j = 0; j < 4; ++j) {
    int k = ty * 4 + j;
    t[k][tx] = W[(size_t)(k0 + k) * N + n0 + tx];
  }
  __syncthreads();
#pragma unroll
  for (int j = 0; j < 4; ++j) {
    int n = ty * 4 + j;
    Wt[(size_t)(n0 + n) * K + k0 + tx] = f2bf(t[tx][n]);
  }
}

// ---------- m97-style bf16 GEMM, 128x128 tile, BK=32 ----------
// MODE 0: C=f32, store acc+bias          (xg)
// MODE 1: C=bf16, store relu(acc+bias)   (d1)
// MODE 2: C=f32, store exp(acc+bias), atomicAdd row sums (fallback path)
template <int MODE>
__global__ __launch_bounds__(256)
void gemm_bf16(const u16* __restrict__ A, const u16* __restrict__ Bt,
               const float* __restrict__ bias, void* __restrict__ Cptr,
               float* __restrict__ rowsum, int M, int N, int K) {
  (void)M;
  __shared__ u16 sA[128 * 32];
  __shared__ u16 sB[128 * 32];
  const int nbn = N >> 7;
  const int nwg = gridDim.x;
  int bid = blockIdx.x;
  int q = nwg >> 3;                         // grids are multiples of 8
  int swz = (bid & 7) * q + (bid >> 3);     // XCD-aware swizzle (bijective)
  int bm = swz / nbn, bn = swz % nbn;
  const int brow = bm << 7, bcol = bn << 7;

  const int tid = threadIdx.x;
  const int lane = tid & 63;
  const int wv = tid >> 6;
  const int wr = (wv >> 1) * 64, wc = (wv & 1) * 64;
  const int ln = lane & 15, kh = lane >> 4;

  const int srow = tid >> 2;                // 0..63
  const int kch = (tid & 3) << 3;           // 0,8,16,24 (elements)

  f32x4 acc[4][4] = {};

  const int nk = K >> 5;
  const u16* Abase = A + (size_t)(brow + srow) * K + kch;
  const u16* Bbase = Bt + (size_t)(bcol + srow) * K + kch;
  const size_t rstride = (size_t)64 * K;
  u16* lA = sA + srow * 32 + kch;
  u16* lB = sB + srow * 32 + kch;

  for (int kt = 0; kt < nk; ++kt) {
    const int k0 = kt << 5;
    gload_lds16(Abase + k0, lA);
    gload_lds16(Abase + rstride + k0, lA + 64 * 32);
    gload_lds16(Bbase + k0, lB);
    gload_lds16(Bbase + rstride + k0, lB + 64 * 32);
    __syncthreads();
    s16x8 aF[4], bF[4];
#pragma unroll
    for (int m = 0; m < 4; ++m)
      aF[m] = *(const s16x8*)(sA + (wr + m * 16 + ln) * 32 + kh * 8);
#pragma unroll
    for (int n = 0; n < 4; ++n)
      bF[n] = *(const s16x8*)(sB + (wc + n * 16 + ln) * 32 + kh * 8);
#pragma unroll
    for (int m = 0; m < 4; ++m)
#pragma unroll
      for (int n = 0; n < 4; ++n)
        acc[m][n] = __builtin_amdgcn_mfma_f32_16x16x32_bf16(aF[m], bF[n], acc[m][n], 0, 0, 0);
    __syncthreads();
  }

  const int browq = brow + wr;
  const int bcolq = bcol + wc;

  if (MODE == 1) {
    u16* O = (u16*)Cptr;
#pragma unroll
    for (int n = 0; n < 4; ++n) {
      int gcol = bcolq + n * 16 + ln;
      float bv = bias[gcol];
#pragma unroll
      for (int m = 0; m < 4; ++m)
#pragma unroll
        for (int r = 0; r < 4; ++r) {
          int grow = browq + m * 16 + kh * 4 + r;
          float v = fmaxf(acc[m][n][r] + bv, 0.f);
          O[(size_t)grow * N + gcol] = f2bf(v);
        }
    }
  } else {
    float* O = (float*)Cptr;
    float rs[4][4] = {};
#pragma unroll
    for (int n = 0; n < 4; ++n) {
      int gcol = bcolq + n * 16 + ln;
      float bv = bias[gcol];
#pragma unroll
      for (int m = 0; m < 4; ++m)
#pragma unroll
        for (int r = 0; r < 4; ++r) {
          int grow = browq + m * 16 + kh * 4 + r;
          float v = acc[m][n][r] + bv;
          if (MODE == 2) { v = __expf(v); rs[m][r] += v; }
          O[(size_t)grow * N + gcol] = v;
        }
    }
    if (MODE == 2) {
#pragma unroll
      for (int m = 0; m < 4; ++m)
#pragma unroll
        for (int r = 0; r < 4; ++r) {
          float v = rs[m][r];
          v += __shfl_xor(v, 1);
          v += __shfl_xor(v, 2);
          v += __shfl_xor(v, 4);
          v += __shfl_xor(v, 8);
          if (ln == 0) atomicAdd(&rowsum[browq + m * 16 + kh * 4 + r], v);
        }
    }
  }
}

// ---------- 256x256-tile logits GEMM, counted-vmcnt 4-buffer pipeline ----------
// BK=32, 4 LDS buffers (32KB each = A 16KB + B 16KB), prefetch 2 K-tiles ahead,
// vmcnt(4) per iter (never 0 in loop), ONE barrier/iter. T2 swizzle: physical
// col16 = logical col16 ^ ((row>>1)&3), applied on global source (write side)
// and ds_read address (read side). 8 waves (2M x 4N), per-wave C = 128x64.
// Epilogue: exp(acc+bias) -> bf16 store + rowsum atomics.
__global__ __launch_bounds__(512, 1)
void gemm256_exp(const u16* __restrict__ A, const u16* __restrict__ Bt,
                 const float* __restrict__ bias, u16* __restrict__ O,
                 float* __restrict__ rowsum, int M, int N, int K) {
  (void)M;
  __shared__ char lds[131072];              // 4 bufs x 32KB
  const int nbn = N >> 8;                   // 125
  const int nwg = gridDim.x;                // 1000 (multiple of 8)
  int bid = blockIdx.x;
  int q = nwg >> 3;
  int swz = (bid & 7) * q + (bid >> 3);     // XCD swizzle (bijective)
  int bm = swz / nbn, bn = swz % nbn;
  const int brow = bm << 8, bcol = bn << 8;

  const int tid = threadIdx.x;
  const int lane = tid & 63;
  const int wv = tid >> 6;                  // 0..7
  const int wm = wv >> 2, wn = wv & 3;
  const int ln = lane & 15, kh = lane >> 4;

  const int nk = K >> 5;                    // 32

  // staging sources: thread stages 4 x 16B chunks per K-tile.
  // j=0,1 -> A region chunks (j&1)*512 + wv*64 + lane; j=2,3 -> B region.
  // chunk c: row = c>>2, pcol = c&3, logical col = pcol ^ ((row>>1)&3).
  const u16* sbase[4];
#pragma unroll
  for (int j = 0; j < 4; ++j) {
    int cc = (j & 1) * 512 + wv * 64 + lane;
    int row = cc >> 2, pcol = cc & 3;
    int lcol = pcol ^ ((row >> 1) & 3);
    sbase[j] = (j < 2 ? A + (size_t)(brow + row) * K
                      : Bt + (size_t)(bcol + row) * K) + lcol * 8;
  }

#define STAGE256(kt, buf)                                                  \
  {                                                                        \
    char* lb = lds + (buf) * 32768 + wv * 1024;                            \
    _Pragma("unroll")                                                      \
    for (int j = 0; j < 4; ++j)                                            \
      gload_lds16(sbase[j] + (kt) * 32, lb + j * 8192);                    \
  }

  f32x4 acc[8][4] = {};

  STAGE256(0, 0);
  STAGE256(1, 1);
  asm volatile("s_waitcnt vmcnt(4)" ::: "memory");   // tile 0 landed
  __syncthreads();

  const char* Ab = lds + (size_t)(wm * 128) * 64;
  const char* Bb = lds + 16384 + (size_t)(wn * 64) * 64;
  const int cswz = (kh ^ ((ln >> 1) & 3)) * 16 + ln * 64;

  for (int t = 0; t < nk; ++t) {
    const int boff = (t & 3) * 32768;
    if (t + 2 < nk) STAGE256(t + 2, (t + 2) & 3);
    s16x8 aF[8], bF[4];
#pragma unroll
    for (int m = 0; m < 8; ++m)
      aF[m] = *(const s16x8*)(Ab + boff + m * 1024 + cswz);
#pragma unroll
    for (int n = 0; n < 4; ++n)
      bF[n] = *(const s16x8*)(Bb + boff + n * 1024 + cswz);
    __builtin_amdgcn_s_setprio(1);
#pragma unroll
    for (int m = 0; m < 8; ++m)
#pragma unroll
      for (int n = 0; n < 4; ++n)
        acc[m][n] = __builtin_amdgcn_mfma_f32_16x16x32_bf16(aF[m], bF[n], acc[m][n], 0, 0, 0);
    __builtin_amdgcn_s_setprio(0);
    if (t + 2 < nk)
      asm volatile("s_waitcnt vmcnt(4)" ::: "memory");   // tile t+1 landed
    else
      asm volatile("s_waitcnt vmcnt(0)" ::: "memory");   // drain tail
    if (t < nk - 1) __syncthreads();
  }

  // ---- fused softmax-exp epilogue ----
  const int browq = brow + wm * 128;
  const int bcolq = bcol + wn * 64;
  float rs[8][4] = {};
#pragma unroll
  for (int n = 0; n < 4; ++n) {
    int gcol = bcolq + n * 16 + ln;
    float bv = bias[gcol];
#pragma unroll
    for (int m = 0; m < 8; ++m)
#pragma unroll
      for (int r = 0; r < 4; ++r) {
        float v = __expf(acc[m][n][r] + bv);
        rs[m][r] += v;
        O[(size_t)(browq + m * 16 + kh * 4 + r) * N + gcol] = f2bf(v);
      }
  }
#pragma unroll
  for (int m = 0; m < 8; ++m)
#pragma unroll
    for (int r = 0; r < 4; ++r) {
      float v = rs[m][r];
      v += __shfl_xor(v, 1);
      v += __shfl_xor(v, 2);
      v += __shfl_xor(v, 4);
      v += __shfl_xor(v, 8);
      if (ln == 0) atomicAdd(&rowsum[browq + m * 16 + kh * 4 + r], v);
    }
#undef STAGE256
}

// ---------- persistent LSTM: 32 WGs x 512 threads, full-K waves (r11) ----------
__global__ __launch_bounds__(512, 1)
void lstm_kernel(const float* __restrict__ xg,      // [2048][4096] f32
                 const u16* __restrict__ Wht,       // [4096][1024] bf16 (n-major)
                 const u64* __restrict__ maskb,     // [16][2] bitmask
                 const float* __restrict__ ench, const float* __restrict__ encc,
                 const float* __restrict__ gamma, const float* __restrict__ beta,
                 const float* __restrict__ mmean, const float* __restrict__ mvar,
                 u32* __restrict__ hbuf32,          // [2][16][512] u32 (linear)
                 u16* __restrict__ hbn,             // [2048][1024] bf16 out
                 u32* __restrict__ cnt) {
  __shared__ char hA[32 * 1024];       // staged h(s), swzB-swizzled

  const int wg = blockIdx.x;           // 0..31
  const int u0 = wg << 5;              // 32 units per WG
  const int tid = threadIdx.x;
  const int lane = tid & 63;
  const int wv = tid >> 6;             // 0..7
  const int ln = lane & 15, khq = lane >> 4;

  const int g = ln & 3;                // gate index (i,f,cc,o)
  const int unit = u0 + wv * 4 + (ln >> 2);

  // ---- Wh preload: 32 x 16B via inline asm ----
  u32x4 bWq[32];
  {
    const u16* wrow = Wht + (size_t)(g * 1024 + unit) * 1024 + khq * 8;
#pragma unroll
    for (int kt = 0; kt < 32; ++kt) {
      const u16* pp = wrow + kt * 32;
      asm volatile("global_load_dwordx4 %0, %1, off" : "=v"(bWq[kt]) : "v"(pp));
    }
    asm volatile("s_waitcnt vmcnt(0)" ::: "memory");
  }

  // per-lane state (g==0 lanes meaningful after shfl combine)
  float cellR[4], holdR[4], xgr[4];
  u64 mA[4], mB[4];
  const float bn_s = gamma[unit] * rsqrtf(mvar[unit] + 1e-3f);
  const float bn_b = beta[unit] - mmean[unit] * bn_s;
  const size_t bstride = (size_t)128 * 4096;
  const float* xbase = xg + (size_t)(khq * 4) * bstride + g * 1024 + unit;
#pragma unroll
  for (int r = 0; r < 4; ++r) {
    int batch = khq * 4 + r;
    cellR[r] = encc[batch * 1024 + unit];
    holdR[r] = ench[batch * 1024 + unit];
    mA[r] = maskb[batch * 2];
    mB[r] = maskb[batch * 2 + 1];
  }
  // initial publish of h(0) into parity-0 buffer
#pragma unroll
  for (int r = 0; r < 4; ++r) {
    u32 w = (u32)f2bf(holdR[r]);
    u32 pw = (u32)__shfl_xor((int)w, 4);   // partner unit+1, same gate
    if ((ln & 7) == 0) {
      int batch = khq * 4 + r;
      AT_ST((u32*)((char*)hbuf32 + batch * 2048 + unit * 2), (w & 0xFFFFu) | (pw << 16));
    }
  }
#pragma unroll
  for (int r = 0; r < 4; ++r) xgr[r] = xbase[r * bstride];   // xg(0) prefetch
  asm volatile("s_waitcnt vmcnt(0)" ::: "memory");
  __syncthreads();
  if (tid == 0) {
    u32 oldv = AT_FAA(cnt);
    if (oldv != 31u) {
      int c = 0;
      while (AT_LD((const u32*)cnt) < 32u) {
        __builtin_amdgcn_s_sleep(1);
        if (++c > (1 << 18)) break;
      }
    }
  }
  __syncthreads();

  for (int s = 0; s < 128; ++s) {
    // ---- stage h(s): 8 back-to-back uncached u64 loads, one waitcnt ----
    u64 st[8];
    {
      const u64* base = (const u64*)((const char*)hbuf32 + (s & 1) * 32768) + tid;
#pragma unroll
      for (int k = 0; k < 8; ++k) {
        const u64* pp = base + k * 512;
        asm volatile("global_load_dwordx2 %0, %1, off sc0 sc1" : "=v"(st[k]) : "v"(pp));
      }
      asm volatile("s_waitcnt vmcnt(0)" ::: "memory");
      __builtin_amdgcn_sched_barrier(0);
#pragma unroll
      for (int k = 0; k < 8; ++k)
        *(u64*)(hA + swzB((tid + k * 512) * 8)) = st[k];
    }
    __syncthreads();                           // (A) hA ready

    // ---- 32 MFMA over full K, 2 chains; A from LDS, B in VGPRs/scratch ----
    f32x4 acc0 = {0.f, 0.f, 0.f, 0.f};
    f32x4 acc1 = {0.f, 0.f, 0.f, 0.f};
#pragma unroll
    for (int kt = 0; kt < 32; kt += 2) {
      s16x8 a0 = *(const s16x8*)(hA + swzB(ln * 2048 + kt * 64 + khq * 16));
      acc0 = __builtin_amdgcn_mfma_f32_16x16x32_bf16(
          a0, __builtin_bit_cast(s16x8, bWq[kt]), acc0, 0, 0, 0);
      s16x8 a1 = *(const s16x8*)(hA + swzB(ln * 2048 + (kt + 1) * 64 + khq * 16));
      acc1 = __builtin_amdgcn_mfma_f32_16x16x32_bf16(
          a1, __builtin_bit_cast(s16x8, bWq[kt + 1]), acc1, 0, 0, 0);
    }
    f32x4 accs = acc0 + acc1;

    // ---- gates fully in-wave (lane quads hold i,f,cc,o) + publish ----
    u32 bnpair[4];
    {
      u16 hbb[4], hbnb[4];
#pragma unroll
      for (int r = 0; r < 4; ++r) {
        float z = accs[r] + xgr[r];
        float sig = 1.f / (1.f + __expf(-z));
        float val = (g == 2) ? fmaxf(z, 0.f) : sig;
        float v1 = __shfl_xor(val, 1);
        float v2 = __shfl_xor(val, 2);
        float v3 = __shfl_xor(val, 3);
        float cnew = v1 * cellR[r] + val * v2;   // f*c + i*cc (g==0 view)
        float hnew = v3 * fmaxf(cnew, 0.f);
        u64 mm = (s < 64) ? mA[r] : mB[r];
        if (!((mm >> (s & 63)) & 1)) { cnew = cellR[r]; hnew = holdR[r]; }
        cellR[r] = cnew;
        holdR[r] = hnew;
        hbb[r] = f2bf(hnew);
        hbnb[r] = f2bf(hnew * bn_s + bn_b);
      }
#pragma unroll
      for (int r = 0; r < 4; ++r) {
        u32 w = (u32)hbb[r] | ((u32)hbnb[r] << 16);
        u32 pw = (u32)__shfl_xor((int)w, 4);
        u32 hpair = (w & 0xFFFFu) | ((pw & 0xFFFFu) << 16);
        bnpair[r] = (w >> 16) | (pw & 0xFFFF0000u);
        if (s < 127 && (ln & 7) == 0) {
          int batch = khq * 4 + r;
          AT_ST((u32*)((char*)hbuf32 + ((s + 1) & 1) * 32768 + batch * 2048 + unit * 2), hpair);
        }
      }
    }

    if (s < 127) {
      asm volatile("s_waitcnt vmcnt(0)" ::: "memory");   // drain h publishes
      __syncthreads();                         // (B) all publishes complete
      u32 oldv = 0xFFFFFFFFu;
      if (tid == 0) oldv = AT_FAA(cnt);
      // deferred hbn stores + xg(s+1) prefetch overlap the poll
      if ((ln & 7) == 0) {
#pragma unroll
        for (int r = 0; r < 4; ++r) {
          int batch = khq * 4 + r;
          *(u32*)((char*)hbn + (size_t)(batch * 128 + s) * 2048 + unit * 2) = bnpair[r];
        }
      }
      {
        const float* xb = xbase + (size_t)(s + 1) * 4096;
#pragma unroll
        for (int r = 0; r < 4; ++r) xgr[r] = xb[r * bstride];
      }
      if (tid == 0) {
        const u32 target = (u32)(s + 2) * 32u;
        if (oldv != target - 1u) {
          int c = 0;
          while (AT_LD((const u32*)cnt) < target) {
            __builtin_amdgcn_s_sleep(1);
            if (++c > (1 << 18)) break;
          }
        }
      }
      __syncthreads();                         // (C) release
    } else if ((ln & 7) == 0) {
      // s == 127: final hbn stores
#pragma unroll
      for (int r = 0; r < 4; ++r) {
        int batch = khq * 4 + r;
        *(u32*)((char*)hbn + (size_t)(batch * 128 + s) * 2048 + unit * 2) = bnpair[r];
      }
    }
  }
}

// ---------- softmax finish ----------

// f32 path (fallback): in-place scale of f32 exp
__global__ void scale_kernel(float* __restrict__ out, const float* __restrict__ rs) {
  const int total4 = 16384000;              // 65,536,000 / 4
  for (int i = blockIdx.x * 256 + threadIdx.x; i < total4; i += gridDim.x * 256) {
    float4* p = (float4*)out + i;
    float4 v = *p;
    int row = i / 8000;                     // 8000 float4 per row
    float sF = 1.0f / rs[row];
    v.x *= sF; v.y *= sF; v.z *= sF; v.w *= sF;
    *p = v;
  }
}

// bf16 path: read bf16 exp, write normalized f32
__global__ void scale_bf_kernel(float* __restrict__ out, const u16* __restrict__ e,
                                const float* __restrict__ rs) {
  const int total8 = 8192000;               // 65,536,000 / 8
  for (int i = blockIdx.x * 256 + threadIdx.x; i < total8; i += gridDim.x * 256) {
    s16x8 v = ((const s16x8*)e)[i];
    int row = i / 4000;                     // 4000 8-groups per row
    float sF = 1.0f / rs[row];
    float4 o0, o1;
    o0.x = bf2f((u16)v[0]) * sF; o0.y = bf2f((u16)v[1]) * sF;
    o0.z = bf2f((u16)v[2]) * sF; o0.w = bf2f((u16)v[3]) * sF;
    o1.x = bf2f((u16)v[4]) * sF; o1.y = bf2f((u16)v[5]) * sF;
    o1.z = bf2f((u16)v[6]) * sF; o1.w = bf2f((u16)v[7]) * sF;
    ((float4*)out)[2 * i] = o0;
    ((float4*)out)[2 * i + 1] = o1;
  }
}

// ---------- launch ----------

extern "C" void kernel_launch(void* const* d_in, const int* in_sizes, int n_in,
                              void* d_out, int out_size, void* d_ws, size_t ws_size,
                              hipStream_t stream) {
  (void)in_sizes; (void)n_in; (void)out_size;
  const int*   inputs = (const int*)d_in[0];
  const float* ench   = (const float*)d_in[1];
  const float* encc   = (const float*)d_in[2];
  const float* emb    = (const float*)d_in[3];
  const float* Wx     = (const float*)d_in[4];
  const float* Wh     = (const float*)d_in[5];
  const float* bb     = (const float*)d_in[6];
  const float* gamma  = (const float*)d_in[7];
  const float* beta   = (const float*)d_in[8];
  const float* mmean  = (const float*)d_in[9];
  const float* mvar   = (const float*)d_in[10];
  const float* W1     = (const float*)d_in[11];
  const float* b1     = (const float*)d_in[12];
  const float* W2     = (const float*)d_in[13];
  const float* b2     = (const float*)d_in[14];
  float* out = (float*)d_out;

  char* p = (char*)d_ws;
  u32*   cnt    = (u32*)(p + 0);            // word 0
  float* rowsum = (float*)(p + 1024);       // 2048 floats; memset covers [0,9216)
  u64*   maskb  = (u64*)(p + 10240);        // 256B, written by mask_kernel
  u32*   hbuf32 = (u32*)(p + 16384);        // 64KB (2 x 32KB parity tiles)
  size_t off = 81920;
  u16*   xbf  = (u16*)(p + off);     off += (size_t)2048 * 512 * 2;     // 2MB
  u16*   Wxt  = (u16*)(p + off);     off += (size_t)4096 * 512 * 2;     // 4MB
  u16*   Wht  = (u16*)(p + off);     off += (size_t)4096 * 1024 * 2;    // 8MB
  u16*   W1t  = (u16*)(p + off);     off += (size_t)1024 * 1024 * 2;    // 2MB
  u16*   W2t  = (u16*)(p + off);     off += (size_t)32000 * 1024 * 2;   // 64MB
  float* xg   = (float*)(p + off);   off += (size_t)2048 * 4096 * 4;    // 32MB
  u16*   hbn  = (u16*)(p + off);     off += (size_t)2048 * 1024 * 2;    // 4MB
  u16*   d1   = (u16*)(p + off);     off += (size_t)2048 * 1024 * 2;    // 4MB
  size_t off_base = off;
  u16*   expbf = (u16*)(p + off);    off += (size_t)2048 * 32000 * 2;   // 125MB (optional)
  if (ws_size < off_base) return;  // insufficient scratch; avoid OOB
  const bool bf16path = (ws_size >= off);

  hipMemsetAsync(d_ws, 0, 9216, stream);  // cnt + rowsum

  embed_kernel<<<512, 256, 0, stream>>>(inputs, emb, xbf);
  mask_kernel<<<1, 64, 0, stream>>>(inputs, maskb);
  transpose_bf16<<<(512 / 32) * (4096 / 32), 256, 0, stream>>>(Wx, Wxt, 512, 4096);
  transpose_bf16<<<(1024 / 32) * (4096 / 32), 256, 0, stream>>>(Wh, Wht, 1024, 4096);
  transpose_bf16<<<(1024 / 32) * (1024 / 32), 256, 0, stream>>>(W1, W1t, 1024, 1024);
  transpose_bf16<<<(1024 / 32) * (32000 / 32), 256, 0, stream>>>(W2, W2t, 1024, 32000);

  gemm_bf16<0><<<16 * 32, 256, 0, stream>>>(xbf, Wxt, bb, xg, nullptr, 2048, 4096, 512);

  lstm_kernel<<<32, 512, 0, stream>>>(xg, Wht, maskb, ench, encc, gamma, beta,
                                      mmean, mvar, hbuf32, hbn, cnt);

  gemm_bf16<1><<<16 * 8, 256, 0, stream>>>(hbn, W1t, b1, d1, nullptr, 2048, 1024, 1024);

  if (bf16path) {
    gemm256_exp<<<8 * 125, 512, 0, stream>>>(d1, W2t, b2, expbf, rowsum, 2048, 32000, 1024);
    scale_bf_kernel<<<2048, 256, 0, stream>>>(out, expbf, rowsum);
  } else {
    gemm_bf16<2><<<16 * 250, 256, 0, stream>>>(d1, W2t, b2, out, rowsum, 2048, 32000, 1024);
    scale_kernel<<<2048, 256, 0, stream>>>(out, rowsum);
  }
}

// Round 13
// 895.227 us; speedup vs baseline: 2.3105x; 1.0034x over previous
//
#include <hip/hip_runtime.h>
#include <hip/hip_bf16.h>
#include <stdint.h>

typedef unsigned short u16;
typedef unsigned int u32;
typedef unsigned long long u64;
typedef __attribute__((ext_vector_type(4))) float f32x4;
typedef __attribute__((ext_vector_type(8))) short s16x8;
typedef __attribute__((ext_vector_type(4))) unsigned int u32x4;

#define AT_LD(p)    __hip_atomic_load((p), __ATOMIC_RELAXED, __HIP_MEMORY_SCOPE_AGENT)
#define AT_ST(p, v) __hip_atomic_store((p), (v), __ATOMIC_RELAXED, __HIP_MEMORY_SCOPE_AGENT)
#define AT_FAA(p)   __hip_atomic_fetch_add((p), 1u, __ATOMIC_RELAXED, __HIP_MEMORY_SCOPE_AGENT)

// ---------- helpers ----------

static __device__ __forceinline__ u16 f2bf(float f) {
  union { float f; unsigned u; } v; v.f = f;
  unsigned r = v.u + 0x7FFFu + ((v.u >> 16) & 1u);
  return (u16)(r >> 16);
}

static __device__ __forceinline__ float bf2f(u16 b) {
  union { unsigned u; float f; } v; v.u = ((u32)b) << 16;
  return v.f;
}

static __device__ __forceinline__ void gload_lds16(const void* g, void* l) {
  __builtin_amdgcn_global_load_lds(
      (const __attribute__((address_space(1))) unsigned int*)(uintptr_t)g,
      (__attribute__((address_space(3))) unsigned int*)(uintptr_t)l,
      16, 0, 0);
}

// bank-balancing swizzle for the 32KB h tile in LDS (r6/r7 proven).
static __device__ __forceinline__ int swzB(int B) {
  int pos = (B >> 4) & 127;
  int row = (B >> 11) & 15;
  int slot = (pos ^ row ^ (pos >> 3)) & 7;
  int npos = (pos & 0x78) | slot;
  return (B & ~0x7F0) | (npos << 4);
}

// ---------- pre-pass kernels ----------

__global__ void embed_kernel(const int* __restrict__ inputs,
                             const float* __restrict__ emb,
                             u16* __restrict__ xbf) {
  int i = blockIdx.x * 256 + threadIdx.x;   // 131072 threads
  int row = i >> 6;
  int e0 = (i & 63) << 3;
  int tok = inputs[row];
  const float* src = emb + (size_t)tok * 512 + e0;
  s16x8 o;
#pragma unroll
  for (int j = 0; j < 8; ++j) o[j] = (short)f2bf(src[j]);
  *(s16x8*)(xbf + (size_t)row * 512 + e0) = o;
}

// bit-pack mask: maskb[b*2+h] bit j = (inputs[b*128 + h*64 + j] != 0)
__global__ void mask_kernel(const int* __restrict__ inputs, u64* __restrict__ mb) {
  int t = threadIdx.x;
  if (t < 32) {
    int b = t >> 1, h = t & 1;
    u64 m = 0;
    for (int j = 0; j < 64; ++j)
      m |= (u64)(inputs[b * 128 + h * 64 + j] != 0) << j;
    mb[t] = m;
  }
}

// Wt[n][k] = bf16(W[k][n]); K,N multiples of 32
__global__ void transpose_bf16(const float* __restrict__ W, u16* __restrict__ Wt,
                               int K, int N) {
  __shared__ float t[32][33];
  int ntn = N >> 5;
  int tn = blockIdx.x % ntn, tk = blockIdx.x / ntn;
  int n0 = tn << 5, k0 = tk << 5;
  int tx = threadIdx.x & 31, ty = threadIdx.x >> 5;  // ty 0..7
#pragma unroll
  for (int j = 0; j < 4; ++j) {
    int k = ty * 4 + j;
    t[k][tx] = W[(size_t)(k0 + k) * N + n0 + tx];
  }
  __syncthreads();
#pragma unroll
  for (int j = 0; j < 4; ++j) {
    int n = ty * 4 + j;
    Wt[(size_t)(n0 + n) * K + k0 + tx] = f2bf(t[tx][n]);
  }
}

// ---------- m97-style bf16 GEMM, 128x128 tile, BK=32 ----------
// MODE 0: C=f32, store acc+bias          (xg)
// MODE 1: C=bf16, store relu(acc+bias)   (d1)
// MODE 2: C=f32, store exp(acc+bias), atomicAdd row sums (fallback path)
template <int MODE>
__global__ __launch_bounds__(256)
void gemm_bf16(const u16* __restrict__ A, const u16* __restrict__ Bt,
               const float* __restrict__ bias, void* __restrict__ Cptr,
               float* __restrict__ rowsum, int M, int N, int K) {
  (void)M;
  __shared__ u16 sA[128 * 32];
  __shared__ u16 sB[128 * 32];
  const int nbn = N >> 7;
  const int nwg = gridDim.x;
  int bid = blockIdx.x;
  int q = nwg >> 3;                         // grids are multiples of 8
  int swz = (bid & 7) * q + (bid >> 3);     // XCD-aware swizzle (bijective)
  int bm = swz / nbn, bn = swz % nbn;
  const int brow = bm << 7, bcol = bn << 7;

  const int tid = threadIdx.x;
  const int lane = tid & 63;
  const int wv = tid >> 6;
  const int wr = (wv >> 1) * 64, wc = (wv & 1) * 64;
  const int ln = lane & 15, kh = lane >> 4;

  const int srow = tid >> 2;                // 0..63
  const int kch = (tid & 3) << 3;           // 0,8,16,24 (elements)

  f32x4 acc[4][4] = {};

  const int nk = K >> 5;
  const u16* Abase = A + (size_t)(brow + srow) * K + kch;
  const u16* Bbase = Bt + (size_t)(bcol + srow) * K + kch;
  const size_t rstride = (size_t)64 * K;
  u16* lA = sA + srow * 32 + kch;
  u16* lB = sB + srow * 32 + kch;

  for (int kt = 0; kt < nk; ++kt) {
    const int k0 = kt << 5;
    gload_lds16(Abase + k0, lA);
    gload_lds16(Abase + rstride + k0, lA + 64 * 32);
    gload_lds16(Bbase + k0, lB);
    gload_lds16(Bbase + rstride + k0, lB + 64 * 32);
    __syncthreads();
    s16x8 aF[4], bF[4];
#pragma unroll
    for (int m = 0; m < 4; ++m)
      aF[m] = *(const s16x8*)(sA + (wr + m * 16 + ln) * 32 + kh * 8);
#pragma unroll
    for (int n = 0; n < 4; ++n)
      bF[n] = *(const s16x8*)(sB + (wc + n * 16 + ln) * 32 + kh * 8);
#pragma unroll
    for (int m = 0; m < 4; ++m)
#pragma unroll
      for (int n = 0; n < 4; ++n)
        acc[m][n] = __builtin_amdgcn_mfma_f32_16x16x32_bf16(aF[m], bF[n], acc[m][n], 0, 0, 0);
    __syncthreads();
  }

  const int browq = brow + wr;
  const int bcolq = bcol + wc;

  if (MODE == 1) {
    u16* O = (u16*)Cptr;
#pragma unroll
    for (int n = 0; n < 4; ++n) {
      int gcol = bcolq + n * 16 + ln;
      float bv = bias[gcol];
#pragma unroll
      for (int m = 0; m < 4; ++m)
#pragma unroll
        for (int r = 0; r < 4; ++r) {
          int grow = browq + m * 16 + kh * 4 + r;
          float v = fmaxf(acc[m][n][r] + bv, 0.f);
          O[(size_t)grow * N + gcol] = f2bf(v);
        }
    }
  } else {
    float* O = (float*)Cptr;
    float rs[4][4] = {};
#pragma unroll
    for (int n = 0; n < 4; ++n) {
      int gcol = bcolq + n * 16 + ln;
      float bv = bias[gcol];
#pragma unroll
      for (int m = 0; m < 4; ++m)
#pragma unroll
        for (int r = 0; r < 4; ++r) {
          int grow = browq + m * 16 + kh * 4 + r;
          float v = acc[m][n][r] + bv;
          if (MODE == 2) { v = __expf(v); rs[m][r] += v; }
          O[(size_t)grow * N + gcol] = v;
        }
    }
    if (MODE == 2) {
#pragma unroll
      for (int m = 0; m < 4; ++m)
#pragma unroll
        for (int r = 0; r < 4; ++r) {
          float v = rs[m][r];
          v += __shfl_xor(v, 1);
          v += __shfl_xor(v, 2);
          v += __shfl_xor(v, 4);
          v += __shfl_xor(v, 8);
          if (ln == 0) atomicAdd(&rowsum[browq + m * 16 + kh * 4 + r], v);
        }
    }
  }
}

// ---------- 256x256-tile logits GEMM, counted-vmcnt 4-buffer pipeline ----------
__global__ __launch_bounds__(512, 1)
void gemm256_exp(const u16* __restrict__ A, const u16* __restrict__ Bt,
                 const float* __restrict__ bias, u16* __restrict__ O,
                 float* __restrict__ rowsum, int M, int N, int K) {
  (void)M;
  __shared__ char lds[131072];              // 4 bufs x 32KB
  const int nbn = N >> 8;                   // 125
  const int nwg = gridDim.x;                // 1000 (multiple of 8)
  int bid = blockIdx.x;
  int q = nwg >> 3;
  int swz = (bid & 7) * q + (bid >> 3);     // XCD swizzle (bijective)
  int bm = swz / nbn, bn = swz % nbn;
  const int brow = bm << 8, bcol = bn << 8;

  const int tid = threadIdx.x;
  const int lane = tid & 63;
  const int wv = tid >> 6;                  // 0..7
  const int wm = wv >> 2, wn = wv & 3;
  const int ln = lane & 15, kh = lane >> 4;

  const int nk = K >> 5;                    // 32

  const u16* sbase[4];
#pragma unroll
  for (int j = 0; j < 4; ++j) {
    int cc = (j & 1) * 512 + wv * 64 + lane;
    int row = cc >> 2, pcol = cc & 3;
    int lcol = pcol ^ ((row >> 1) & 3);
    sbase[j] = (j < 2 ? A + (size_t)(brow + row) * K
                      : Bt + (size_t)(bcol + row) * K) + lcol * 8;
  }

#define STAGE256(kt, buf)                                                  \
  {                                                                        \
    char* lb = lds + (buf) * 32768 + wv * 1024;                            \
    _Pragma("unroll")                                                      \
    for (int j = 0; j < 4; ++j)                                            \
      gload_lds16(sbase[j] + (kt) * 32, lb + j * 8192);                    \
  }

  f32x4 acc[8][4] = {};

  STAGE256(0, 0);
  STAGE256(1, 1);
  asm volatile("s_waitcnt vmcnt(4)" ::: "memory");   // tile 0 landed
  __syncthreads();

  const char* Ab = lds + (size_t)(wm * 128) * 64;
  const char* Bb = lds + 16384 + (size_t)(wn * 64) * 64;
  const int cswz = (kh ^ ((ln >> 1) & 3)) * 16 + ln * 64;

  for (int t = 0; t < nk; ++t) {
    const int boff = (t & 3) * 32768;
    if (t + 2 < nk) STAGE256(t + 2, (t + 2) & 3);
    s16x8 aF[8], bF[4];
#pragma unroll
    for (int m = 0; m < 8; ++m)
      aF[m] = *(const s16x8*)(Ab + boff + m * 1024 + cswz);
#pragma unroll
    for (int n = 0; n < 4; ++n)
      bF[n] = *(const s16x8*)(Bb + boff + n * 1024 + cswz);
    __builtin_amdgcn_s_setprio(1);
#pragma unroll
    for (int m = 0; m < 8; ++m)
#pragma unroll
      for (int n = 0; n < 4; ++n)
        acc[m][n] = __builtin_amdgcn_mfma_f32_16x16x32_bf16(aF[m], bF[n], acc[m][n], 0, 0, 0);
    __builtin_amdgcn_s_setprio(0);
    if (t + 2 < nk)
      asm volatile("s_waitcnt vmcnt(4)" ::: "memory");   // tile t+1 landed
    else
      asm volatile("s_waitcnt vmcnt(0)" ::: "memory");   // drain tail
    if (t < nk - 1) __syncthreads();
  }

  // ---- fused softmax-exp epilogue ----
  const int browq = brow + wm * 128;
  const int bcolq = bcol + wn * 64;
  float rs[8][4] = {};
#pragma unroll
  for (int n = 0; n < 4; ++n) {
    int gcol = bcolq + n * 16 + ln;
    float bv = bias[gcol];
#pragma unroll
    for (int m = 0; m < 8; ++m)
#pragma unroll
      for (int r = 0; r < 4; ++r) {
        float v = __expf(acc[m][n][r] + bv);
        rs[m][r] += v;
        O[(size_t)(browq + m * 16 + kh * 4 + r) * N + gcol] = f2bf(v);
      }
  }
#pragma unroll
  for (int m = 0; m < 8; ++m)
#pragma unroll
    for (int r = 0; r < 4; ++r) {
      float v = rs[m][r];
      v += __shfl_xor(v, 1);
      v += __shfl_xor(v, 2);
      v += __shfl_xor(v, 4);
      v += __shfl_xor(v, 8);
      if (ln == 0) atomicAdd(&rowsum[browq + m * 16 + kh * 4 + r], v);
    }
#undef STAGE256
}

// ---------- persistent LSTM: 32 WGs x 512 threads, full-K waves ----------
// waves_per_eu(2,2): this persistent kernel runs exactly 8 waves on 4 SIMDs
// (2/SIMD) -> VGPR budget 256/lane. Frees the allocator to keep bWq[32]
// (128 VGPRs) RESIDENT instead of spilling to scratch (r11: VGPR=116 ->
// 256KB/WG/step re-read through the CU port = the measured ~1.7us/step floor).
__global__ __attribute__((amdgpu_flat_work_group_size(512, 512), amdgpu_waves_per_eu(2, 2)))
void lstm_kernel(const float* __restrict__ xg,      // [2048][4096] f32
                 const u16* __restrict__ Wht,       // [4096][1024] bf16 (n-major)
                 const u64* __restrict__ maskb,     // [16][2] bitmask
                 const float* __restrict__ ench, const float* __restrict__ encc,
                 const float* __restrict__ gamma, const float* __restrict__ beta,
                 const float* __restrict__ mmean, const float* __restrict__ mvar,
                 u32* __restrict__ hbuf32,          // [2][16][512] u32 (linear)
                 u16* __restrict__ hbn,             // [2048][1024] bf16 out
                 u32* __restrict__ cnt) {
  __shared__ char hA[32 * 1024];       // staged h(s), swzB-swizzled

  const int wg = blockIdx.x;           // 0..31
  const int u0 = wg << 5;              // 32 units per WG
  const int tid = threadIdx.x;
  const int lane = tid & 63;
  const int wv = tid >> 6;             // 0..7
  const int ln = lane & 15, khq = lane >> 4;

  const int g = ln & 3;                // gate index (i,f,cc,o)
  const int unit = u0 + wv * 4 + (ln >> 2);

  // ---- Wh preload: 32 x 16B via inline asm -> must stay in VGPRs ----
  u32x4 bWq[32];
  {
    const u16* wrow = Wht + (size_t)(g * 1024 + unit) * 1024 + khq * 8;
#pragma unroll
    for (int kt = 0; kt < 32; ++kt) {
      const u16* pp = wrow + kt * 32;
      asm volatile("global_load_dwordx4 %0, %1, off" : "=v"(bWq[kt]) : "v"(pp));
    }
    asm volatile("s_waitcnt vmcnt(0)" ::: "memory");
  }

  // per-lane state (g==0 lanes meaningful after shfl combine)
  float cellR[4], holdR[4], xgr[4];
  u64 mA[4], mB[4];
  const float bn_s = gamma[unit] * rsqrtf(mvar[unit] + 1e-3f);
  const float bn_b = beta[unit] - mmean[unit] * bn_s;
  const size_t bstride = (size_t)128 * 4096;
  const float* xbase = xg + (size_t)(khq * 4) * bstride + g * 1024 + unit;
#pragma unroll
  for (int r = 0; r < 4; ++r) {
    int batch = khq * 4 + r;
    cellR[r] = encc[batch * 1024 + unit];
    holdR[r] = ench[batch * 1024 + unit];
    mA[r] = maskb[batch * 2];
    mB[r] = maskb[batch * 2 + 1];
  }
  // initial publish of h(0) into parity-0 buffer
#pragma unroll
  for (int r = 0; r < 4; ++r) {
    u32 w = (u32)f2bf(holdR[r]);
    u32 pw = (u32)__shfl_xor((int)w, 4);   // partner unit+1, same gate
    if ((ln & 7) == 0) {
      int batch = khq * 4 + r;
      AT_ST((u32*)((char*)hbuf32 + batch * 2048 + unit * 2), (w & 0xFFFFu) | (pw << 16));
    }
  }
#pragma unroll
  for (int r = 0; r < 4; ++r) xgr[r] = xbase[r * bstride];   // xg(0) prefetch
  asm volatile("s_waitcnt vmcnt(0)" ::: "memory");
  __syncthreads();
  if (tid == 0) {
    u32 oldv = AT_FAA(cnt);
    if (oldv != 31u) {
      int c = 0;
      while (AT_LD((const u32*)cnt) < 32u) {
        __builtin_amdgcn_s_sleep(1);
        if (++c > (1 << 18)) break;
      }
    }
  }
  __syncthreads();

  for (int s = 0; s < 128; ++s) {
    // ---- stage h(s): 8 back-to-back uncached u64 loads, one waitcnt ----
    u64 st[8];
    {
      const u64* base = (const u64*)((const char*)hbuf32 + (s & 1) * 32768) + tid;
#pragma unroll
      for (int k = 0; k < 8; ++k) {
        const u64* pp = base + k * 512;
        asm volatile("global_load_dwordx2 %0, %1, off sc0 sc1" : "=v"(st[k]) : "v"(pp));
      }
      asm volatile("s_waitcnt vmcnt(0)" ::: "memory");
      __builtin_amdgcn_sched_barrier(0);
#pragma unroll
      for (int k = 0; k < 8; ++k)
        *(u64*)(hA + swzB((tid + k * 512) * 8)) = st[k];
    }
    __syncthreads();                           // (A) hA ready

    // ---- 32 MFMA over full K, 2 chains; A from LDS, B resident in VGPRs ----
    f32x4 acc0 = {0.f, 0.f, 0.f, 0.f};
    f32x4 acc1 = {0.f, 0.f, 0.f, 0.f};
#pragma unroll
    for (int kt = 0; kt < 32; kt += 2) {
      s16x8 a0 = *(const s16x8*)(hA + swzB(ln * 2048 + kt * 64 + khq * 16));
      acc0 = __builtin_amdgcn_mfma_f32_16x16x32_bf16(
          a0, __builtin_bit_cast(s16x8, bWq[kt]), acc0, 0, 0, 0);
      s16x8 a1 = *(const s16x8*)(hA + swzB(ln * 2048 + (kt + 1) * 64 + khq * 16));
      acc1 = __builtin_amdgcn_mfma_f32_16x16x32_bf16(
          a1, __builtin_bit_cast(s16x8, bWq[kt + 1]), acc1, 0, 0, 0);
    }
    f32x4 accs = acc0 + acc1;

    // ---- gates fully in-wave (lane quads hold i,f,cc,o) + publish ----
    u32 bnpair[4];
    {
      u16 hbb[4], hbnb[4];
#pragma unroll
      for (int r = 0; r < 4; ++r) {
        float z = accs[r] + xgr[r];
        float sig = 1.f / (1.f + __expf(-z));
        float val = (g == 2) ? fmaxf(z, 0.f) : sig;
        float v1 = __shfl_xor(val, 1);
        float v2 = __shfl_xor(val, 2);
        float v3 = __shfl_xor(val, 3);
        float cnew = v1 * cellR[r] + val * v2;   // f*c + i*cc (g==0 view)
        float hnew = v3 * fmaxf(cnew, 0.f);
        u64 mm = (s < 64) ? mA[r] : mB[r];
        if (!((mm >> (s & 63)) & 1)) { cnew = cellR[r]; hnew = holdR[r]; }
        cellR[r] = cnew;
        holdR[r] = hnew;
        hbb[r] = f2bf(hnew);
        hbnb[r] = f2bf(hnew * bn_s + bn_b);
      }
#pragma unroll
      for (int r = 0; r < 4; ++r) {
        u32 w = (u32)hbb[r] | ((u32)hbnb[r] << 16);
        u32 pw = (u32)__shfl_xor((int)w, 4);
        u32 hpair = (w & 0xFFFFu) | ((pw & 0xFFFFu) << 16);
        bnpair[r] = (w >> 16) | (pw & 0xFFFF0000u);
        if (s < 127 && (ln & 7) == 0) {
          int batch = khq * 4 + r;
          AT_ST((u32*)((char*)hbuf32 + ((s + 1) & 1) * 32768 + batch * 2048 + unit * 2), hpair);
        }
      }
    }

    if (s < 127) {
      asm volatile("s_waitcnt vmcnt(0)" ::: "memory");   // drain h publishes
      __syncthreads();                         // (B) all publishes complete
      u32 oldv = 0xFFFFFFFFu;
      if (tid == 0) oldv = AT_FAA(cnt);
      // deferred hbn stores + xg(s+1) prefetch overlap the poll
      if ((ln & 7) == 0) {
#pragma unroll
        for (int r = 0; r < 4; ++r) {
          int batch = khq * 4 + r;
          *(u32*)((char*)hbn + (size_t)(batch * 128 + s) * 2048 + unit * 2) = bnpair[r];
        }
      }
      {
        const float* xb = xbase + (size_t)(s + 1) * 4096;
#pragma unroll
        for (int r = 0; r < 4; ++r) xgr[r] = xb[r * bstride];
      }
      if (tid == 0) {
        const u32 target = (u32)(s + 2) * 32u;
        if (oldv != target - 1u) {
          int c = 0;
          while (AT_LD((const u32*)cnt) < target) {
            __builtin_amdgcn_s_sleep(1);
            if (++c > (1 << 18)) break;
          }
        }
      }
      __syncthreads();                         // (C) release
    } else if ((ln & 7) == 0) {
      // s == 127: final hbn stores
#pragma unroll
      for (int r = 0; r < 4; ++r) {
        int batch = khq * 4 + r;
        *(u32*)((char*)hbn + (size_t)(batch * 128 + s) * 2048 + unit * 2) = bnpair[r];
      }
    }
  }
}

// ---------- softmax finish ----------

// f32 path (fallback): in-place scale of f32 exp
__global__ void scale_kernel(float* __restrict__ out, const float* __restrict__ rs) {
  const int total4 = 16384000;              // 65,536,000 / 4
  for (int i = blockIdx.x * 256 + threadIdx.x; i < total4; i += gridDim.x * 256) {
    float4* p = (float4*)out + i;
    float4 v = *p;
    int row = i / 8000;                     // 8000 float4 per row
    float sF = 1.0f / rs[row];
    v.x *= sF; v.y *= sF; v.z *= sF; v.w *= sF;
    *p = v;
  }
}

// bf16 path: read bf16 exp, write normalized f32
__global__ void scale_bf_kernel(float* __restrict__ out, const u16* __restrict__ e,
                                const float* __restrict__ rs) {
  const int total8 = 8192000;               // 65,536,000 / 8
  for (int i = blockIdx.x * 256 + threadIdx.x; i < total8; i += gridDim.x * 256) {
    s16x8 v = ((const s16x8*)e)[i];
    int row = i / 4000;                     // 4000 8-groups per row
    float sF = 1.0f / rs[row];
    float4 o0, o1;
    o0.x = bf2f((u16)v[0]) * sF; o0.y = bf2f((u16)v[1]) * sF;
    o0.z = bf2f((u16)v[2]) * sF; o0.w = bf2f((u16)v[3]) * sF;
    o1.x = bf2f((u16)v[4]) * sF; o1.y = bf2f((u16)v[5]) * sF;
    o1.z = bf2f((u16)v[6]) * sF; o1.w = bf2f((u16)v[7]) * sF;
    ((float4*)out)[2 * i] = o0;
    ((float4*)out)[2 * i + 1] = o1;
  }
}

// ---------- launch ----------

extern "C" void kernel_launch(void* const* d_in, const int* in_sizes, int n_in,
                              void* d_out, int out_size, void* d_ws, size_t ws_size,
                              hipStream_t stream) {
  (void)in_sizes; (void)n_in; (void)out_size;
  const int*   inputs = (const int*)d_in[0];
  const float* ench   = (const float*)d_in[1];
  const float* encc   = (const float*)d_in[2];
  const float* emb    = (const float*)d_in[3];
  const float* Wx     = (const float*)d_in[4];
  const float* Wh     = (const float*)d_in[5];
  const float* bb     = (const float*)d_in[6];
  const float* gamma  = (const float*)d_in[7];
  const float* beta   = (const float*)d_in[8];
  const float* mmean  = (const float*)d_in[9];
  const float* mvar   = (const float*)d_in[10];
  const float* W1     = (const float*)d_in[11];
  const float* b1     = (const float*)d_in[12];
  const float* W2     = (const float*)d_in[13];
  const float* b2     = (const float*)d_in[14];
  float* out = (float*)d_out;

  char* p = (char*)d_ws;
  u32*   cnt    = (u32*)(p + 0);            // word 0
  float* rowsum = (float*)(p + 1024);       // 2048 floats; memset covers [0,9216)
  u64*   maskb  = (u64*)(p + 10240);        // 256B, written by mask_kernel
  u32*   hbuf32 = (u32*)(p + 16384);        // 64KB (2 x 32KB parity tiles)
  size_t off = 81920;
  u16*   xbf  = (u16*)(p + off);     off += (size_t)2048 * 512 * 2;     // 2MB
  u16*   Wxt  = (u16*)(p + off);     off += (size_t)4096 * 512 * 2;     // 4MB
  u16*   Wht  = (u16*)(p + off);     off += (size_t)4096 * 1024 * 2;    // 8MB
  u16*   W1t  = (u16*)(p + off);     off += (size_t)1024 * 1024 * 2;    // 2MB
  u16*   W2t  = (u16*)(p + off);     off += (size_t)32000 * 1024 * 2;   // 64MB
  float* xg   = (float*)(p + off);   off += (size_t)2048 * 4096 * 4;    // 32MB
  u16*   hbn  = (u16*)(p + off);     off += (size_t)2048 * 1024 * 2;    // 4MB
  u16*   d1   = (u16*)(p + off);     off += (size_t)2048 * 1024 * 2;    // 4MB
  size_t off_base = off;
  u16*   expbf = (u16*)(p + off);    off += (size_t)2048 * 32000 * 2;   // 125MB (optional)
  if (ws_size < off_base) return;  // insufficient scratch; avoid OOB
  const bool bf16path = (ws_size >= off);

  hipMemsetAsync(d_ws, 0, 9216, stream);  // cnt + rowsum

  embed_kernel<<<512, 256, 0, stream>>>(inputs, emb, xbf);
  mask_kernel<<<1, 64, 0, stream>>>(inputs, maskb);
  transpose_bf16<<<(512 / 32) * (4096 / 32), 256, 0, stream>>>(Wx, Wxt, 512, 4096);
  transpose_bf16<<<(1024 / 32) * (4096 / 32), 256, 0, stream>>>(Wh, Wht, 1024, 4096);
  transpose_bf16<<<(1024 / 32) * (1024 / 32), 256, 0, stream>>>(W1, W1t, 1024, 1024);
  transpose_bf16<<<(1024 / 32) * (32000 / 32), 256, 0, stream>>>(W2, W2t, 1024, 32000);

  gemm_bf16<0><<<16 * 32, 256, 0, stream>>>(xbf, Wxt, bb, xg, nullptr, 2048, 4096, 512);

  lstm_kernel<<<32, 512, 0, stream>>>(xg, Wht, maskb, ench, encc, gamma, beta,
                                      mmean, mvar, hbuf32, hbn, cnt);

  gemm_bf16<1><<<16 * 8, 256, 0, stream>>>(hbn, W1t, b1, d1, nullptr, 2048, 1024, 1024);

  if (bf16path) {
    gemm256_exp<<<8 * 125, 512, 0, stream>>>(d1, W2t, b2, expbf, rowsum, 2048, 32000, 1024);
    scale_bf_kernel<<<2048, 256, 0, stream>>>(out, expbf, rowsum);
  } else {
    gemm_bf16<2><<<16 * 250, 256, 0, stream>>>(d1, W2t, b2, out, rowsum, 2048, 32000, 1024);
    scale_kernel<<<2048, 256, 0, stream>>>(out, rowsum);
  }
}